// Round 4
// baseline (739.611 us; speedup 1.0000x reference)
//
#include <hip/hip_runtime.h>

#define B_ 4
#define S_ 2048
#define D_ 1024
#define H_ 16
#define KD_ 64
#define P_ 1024
#define M_ (B_*S_)

typedef unsigned short u16;
typedef unsigned int u32;
typedef __attribute__((ext_vector_type(2))) unsigned u32x2;
typedef __attribute__((ext_vector_type(4))) float f32x4;
typedef __attribute__((ext_vector_type(8))) __bf16 bf16x8;

__device__ __forceinline__ u16 f2bf(float f) {
  u32 x = __float_as_uint(f);
  return (u16)((x + 0x7fffu + ((x >> 16) & 1u)) >> 16);
}

__device__ __forceinline__ void gl_lds16(const u16* g, u16* l) {
  __builtin_amdgcn_global_load_lds((__attribute__((address_space(1))) void*)g,
                                   (__attribute__((address_space(3))) void*)l, 16, 0, 0);
}

// pack bf16(b)<<16 | bf16(a), round-to-nearest (+0x8000 then take hi16 via v_perm)
__device__ __forceinline__ u32 pkbf(float a, float b) {
  return __builtin_amdgcn_perm(__float_as_uint(b) + 0x8000u,
                               __float_as_uint(a) + 0x8000u, 0x07060302u);
}

// Quad redistribution for P -> PV B-operand (proven in rounds 2-3).
// After this: a = [a@q0, a@q2, b@q0, b@q2], b = [a@q1, a@q3, b@q1, b@q3]
// (x@qN = value of x at source quad N, same l16).
#if __has_builtin(__builtin_amdgcn_permlane32_swap) && __has_builtin(__builtin_amdgcn_permlane16_swap)
__device__ __forceinline__ void plswap(u32& a, u32& b) {
  u32x2 r32 = __builtin_amdgcn_permlane32_swap(a, b, false, false);
  u32x2 r16 = __builtin_amdgcn_permlane16_swap(r32[0], r32[1], false, false);
  a = r16[0]; b = r16[1];
}
#else
__device__ __forceinline__ void plswap(u32& a, u32& b) {
  const int l = threadIdx.x & 63;
  const int quad = l >> 4, l16 = l & 15;
  int i0 = (((quad & 1) * 32) + l16) * 4;
  int i1 = i0 + 64;
  int a_lo = __builtin_amdgcn_ds_bpermute(i0, (int)a);
  int b_lo = __builtin_amdgcn_ds_bpermute(i0, (int)b);
  int a_hi = __builtin_amdgcn_ds_bpermute(i1, (int)a);
  int b_hi = __builtin_amdgcn_ds_bpermute(i1, (int)b);
  u32 na = (quad < 2) ? (u32)a_lo : (u32)b_lo;
  u32 nb = (quad < 2) ? (u32)a_hi : (u32)b_hi;
  a = na; b = nb;
}
#endif

// ---------------- fp32 -> bf16 convert, 3 tensors in one launch ----------------
__global__ void cvt3_kernel(const float* __restrict__ q, const float* __restrict__ k,
                            const float* __restrict__ v,
                            u16* __restrict__ Xq, u16* __restrict__ Xk, u16* __restrict__ Xv) {
  const int z = blockIdx.y;
  const float* in = z == 0 ? q : z == 1 ? k : v;
  u16* out = z == 0 ? Xq : z == 1 ? Xk : Xv;
  int i = blockIdx.x * 256 + threadIdx.x;
  float4 vv = ((const float4*)in)[i];
  ((u32*)out)[i*2+0] = (u32)f2bf(vv.x) | ((u32)f2bf(vv.y) << 16);
  ((u32*)out)[i*2+1] = (u32)f2bf(vv.z) | ((u32)f2bf(vv.w) << 16);
}

// ---------------- transpose 1024x1024 fp32 -> bf16 [C][R], 4 weights ----------------
__global__ void transpose_cvt4(const float* __restrict__ Wq, const float* __restrict__ Wk,
                               const float* __restrict__ Wv, const float* __restrict__ Wo,
                               u16* __restrict__ WqT, u16* __restrict__ WkT,
                               u16* __restrict__ WvT, u16* __restrict__ WoT) {
  const int z = blockIdx.z;
  const float* in = z == 0 ? Wq : z == 1 ? Wk : z == 2 ? Wv : Wo;
  u16* out = z == 0 ? WqT : z == 1 ? WkT : z == 2 ? WvT : WoT;
  __shared__ float tile[32][33];
  int bx = blockIdx.x * 32, by = blockIdx.y * 32;
  int tx = threadIdx.x, ty = threadIdx.y; // block (32,8)
  #pragma unroll
  for (int kk = 0; kk < 4; ++kk)
    tile[ty + kk*8][tx] = in[(by + ty + kk*8) * 1024 + bx + tx];
  __syncthreads();
  #pragma unroll
  for (int kk = 0; kk < 4; ++kk)
    out[(bx + ty + kk*8) * 1024 + by + tx] = f2bf(tile[tx][ty + kk*8]);
}

// ---------------- QKV projection GEMM (batched, z selects), m97 pattern ----------------
// z=0: Q -> Qb [row][P]; z=1: K -> Kb [row][P]; z=2: V -> Vt [b][h][d][s] (transposed!)
__global__ __launch_bounds__(256) void gemm_qkv(
    const u16* __restrict__ Xq, const u16* __restrict__ Xk, const u16* __restrict__ Xv,
    const u16* __restrict__ WqT, const u16* __restrict__ WkT, const u16* __restrict__ WvT,
    const float* __restrict__ bq, const float* __restrict__ bk, const float* __restrict__ bv,
    u16* __restrict__ Qb, u16* __restrict__ Kb, u16* __restrict__ Vt)
{
  constexpr int K = 1024, N = 1024, BK = 32;
  const int z = blockIdx.z;
  const u16* A  = z == 0 ? Xq  : z == 1 ? Xk  : Xv;
  const u16* Bt = z == 0 ? WqT : z == 1 ? WkT : WvT;
  const float* bias = z == 0 ? bq : z == 1 ? bk : bv;

  __shared__ alignas(16) u16 As[128*BK];
  __shared__ alignas(16) u16 Bs[128*BK];
  const int tid = threadIdx.x;
  const int w = tid >> 6, l = tid & 63;
  const int quad = l >> 4, l16 = l & 15;
  const int wm = (w >> 1) * 64, wn = (w & 1) * 64;
  const long mBase = (long)blockIdx.x * 128;
  const int  nBase = blockIdx.y * 128;

  f32x4 acc[4][4] = {};
  const int off0 = w*1024 + l*16;

  for (int kb = 0; kb < K/BK; ++kb) {
    __syncthreads();
    #pragma unroll
    for (int p = 0; p < 2; ++p) {
      int off = p*4096 + off0;
      int row = off >> 6;
      int cb  = off & 63;
      const u16* ga = A  + (mBase + row)*K + kb*BK + (cb >> 1);
      const u16* gb = Bt + ((long)(nBase + row))*K + kb*BK + (cb >> 1);
      gl_lds16(ga, (u16*)((char*)As + p*4096 + w*1024));
      gl_lds16(gb, (u16*)((char*)Bs + p*4096 + w*1024));
    }
    __syncthreads();
    bf16x8 af[4], bf[4];
    #pragma unroll
    for (int i = 0; i < 4; ++i) af[i] = *(const bf16x8*)&As[(wm + i*16 + l16)*BK + quad*8];
    #pragma unroll
    for (int j = 0; j < 4; ++j) bf[j] = *(const bf16x8*)&Bs[(wn + j*16 + l16)*BK + quad*8];
    #pragma unroll
    for (int i = 0; i < 4; ++i)
      #pragma unroll
      for (int j = 0; j < 4; ++j)
        acc[i][j] = __builtin_amdgcn_mfma_f32_16x16x32_bf16(af[i], bf[j], acc[i][j], 0, 0, 0);
  }

  if (z < 2) {
    u16* Cout = z == 0 ? Qb : Kb;
    #pragma unroll
    for (int i = 0; i < 4; ++i)
      #pragma unroll
      for (int j = 0; j < 4; ++j)
        #pragma unroll
        for (int r = 0; r < 4; ++r) {
          long row = mBase + wm + i*16 + quad*4 + r;
          int  col = nBase + wn + j*16 + l16;
          Cout[row*N + col] = f2bf(acc[i][j][r] + bias[col]);
        }
  } else {
    // V: write transposed per head: Vt[(b*1024 + h*64 + d)*2048 + s]; 4 consecutive s -> 8B stores
    #pragma unroll
    for (int i = 0; i < 4; ++i)
      #pragma unroll
      for (int j = 0; j < 4; ++j) {
        int  col  = nBase + wn + j*16 + l16;       // = h*64+d
        long row0 = mBase + wm + i*16 + quad*4;    // token; +r consecutive
        int  bb = (int)(row0 >> 11);
        int  ss = (int)(row0 & 2047);
        float bcol = bias[col];
        float v0 = acc[i][j][0] + bcol, v1 = acc[i][j][1] + bcol;
        float v2 = acc[i][j][2] + bcol, v3 = acc[i][j][3] + bcol;
        uint2 pk;
        pk.x = (u32)f2bf(v0) | ((u32)f2bf(v1) << 16);
        pk.y = (u32)f2bf(v2) | ((u32)f2bf(v3) << 16);
        *(uint2*)&Vt[((long)(bb*16) * 64 + col) * 2048 + ss] = pk;
      }
  }
}

// ---------------- output projection GEMM (fp32 out) ----------------
__global__ __launch_bounds__(256) void gemm_out(const u16* __restrict__ A,
                                                const u16* __restrict__ Bt,
                                                const float* __restrict__ bias,
                                                float* __restrict__ Cout)
{
  constexpr int K = 1024, N = 1024, BK = 32;
  __shared__ alignas(16) u16 As[128*BK];
  __shared__ alignas(16) u16 Bs[128*BK];
  const int tid = threadIdx.x;
  const int w = tid >> 6, l = tid & 63;
  const int quad = l >> 4, l16 = l & 15;
  const int wm = (w >> 1) * 64, wn = (w & 1) * 64;
  const long mBase = (long)blockIdx.x * 128;
  const int  nBase = blockIdx.y * 128;

  f32x4 acc[4][4] = {};
  const int off0 = w*1024 + l*16;

  for (int kb = 0; kb < K/BK; ++kb) {
    __syncthreads();
    #pragma unroll
    for (int p = 0; p < 2; ++p) {
      int off = p*4096 + off0;
      int row = off >> 6;
      int cb  = off & 63;
      const u16* ga = A  + (mBase + row)*K + kb*BK + (cb >> 1);
      const u16* gb = Bt + ((long)(nBase + row))*K + kb*BK + (cb >> 1);
      gl_lds16(ga, (u16*)((char*)As + p*4096 + w*1024));
      gl_lds16(gb, (u16*)((char*)Bs + p*4096 + w*1024));
    }
    __syncthreads();
    bf16x8 af[4], bf[4];
    #pragma unroll
    for (int i = 0; i < 4; ++i) af[i] = *(const bf16x8*)&As[(wm + i*16 + l16)*BK + quad*8];
    #pragma unroll
    for (int j = 0; j < 4; ++j) bf[j] = *(const bf16x8*)&Bs[(wn + j*16 + l16)*BK + quad*8];
    #pragma unroll
    for (int i = 0; i < 4; ++i)
      #pragma unroll
      for (int j = 0; j < 4; ++j)
        acc[i][j] = __builtin_amdgcn_mfma_f32_16x16x32_bf16(af[i], bf[j], acc[i][j], 0, 0, 0);
  }

  #pragma unroll
  for (int i = 0; i < 4; ++i)
    #pragma unroll
    for (int j = 0; j < 4; ++j)
      #pragma unroll
      for (int r = 0; r < 4; ++r) {
        long row = mBase + wm + i*16 + quad*4 + r;
        int  col = nBase + wn + j*16 + l16;
        Cout[row*N + col] = acc[i][j][r] + bias[col];
      }
}

// ---------------- flash attention: 4-wave blocks, register-only P (no LDS) ----------------
// grid 1024 = qtr(16, qt=15 first) x [b(4) x h(16)]; 256 threads = 4 waves.
// Wave w (= threadIdx.x>>6) owns q sub-tile w*32 of the 128-q tile: per-wave geometry
// IDENTICAL to the round-3 kernel (32 q-rows/wave) — only launch grouping changed.
// All 4 waves stream the SAME K/V tiles (same b,h,kt) in near-lockstep -> L1 dedup
// (K 16KB + V 16KB fits 32KB L1), and 4 waves/block packs 16 waves/CU vs ~9 before.
// S^T = K*Q^T (swapped operands): lane(quad,l16) reg r holds S^T[key=j*16+quad*4+r][q=l16].
// PV B-operand via pure quad permutation (plswap pairs) — no LDS, no barriers, no lgkm waits.
// Static-shift softmax: exponent = c1*s - sl2*k (ALiBi grows toward k=0), bounded;
// no max-tracking, no rescale; distant-key underflow to 0 is exact.
__global__ __launch_bounds__(256, 8) void attn_kernel(const u16* __restrict__ Qb,
                                                      const u16* __restrict__ Kb,
                                                      const u16* __restrict__ Vt,
                                                      u16* __restrict__ Ob)
{
  const int n = blockIdx.x;
  const int qt = 15 - (n >> 6);
  const int r6 = n & 63;
  const int b = r6 >> 4, h = r6 & 15;
  const int w = threadIdx.x >> 6;
  const int l = threadIdx.x & 63;
  const int quad = l >> 4, l16 = l & 15;
  const float LOG2E = 1.44269504089f;
  const float slope = exp2f(-0.5f * (float)(h + 1));
  const float c1  = 0.125f * LOG2E;
  const float sl2 = slope * LOG2E;
  const float rs1 = sl2, rs2 = 2.f*sl2, rs3 = 3.f*sl2;

  const int q0 = qt*128 + w*32;
  const u16* Qp = Qb + ((long)(b*S_ + q0))*P_ + h*KD_;
  const u16* Kp = Kb + ((long)(b*S_))*P_ + h*KD_;
  const u16* Vp = Vt + ((long)(b*H_ + h))*KD_*S_;

  // Q fragments (MFMA B-operand for S^T = K*Q^T)
  bf16x8 qf[2][2];
  #pragma unroll
  for (int i = 0; i < 2; ++i)
    #pragma unroll
    for (int kk = 0; kk < 2; ++kk)
      qf[i][kk] = *(const bf16x8*)&Qp[(long)(i*16 + l16)*P_ + kk*32 + quad*8];

  f32x4 o[2][4] = {};           // O^T accumulators: rows d (jn*16+quad*4+r), cols q=l16
  float lsum[2] = {0.f, 0.f};

  // -------- full (non-diagonal) key tiles --------
  for (int kt = 0; kt < qt; ++kt) {
    const u16* kts = Kp + (long)(kt*128 + l16)*P_;
    const float kbase = (float)(kt*128);
    #pragma unroll
    for (int ks = 0; ks < 4; ++ks) {
      u32 pw[2][2][2];          // [i][jp][c]
      #pragma unroll
      for (int jp = 0; jp < 2; ++jp) {
        const int j = 2*ks + jp;
        const u16* kp = kts + (long)(j*16)*P_;
        bf16x8 kf0 = *(const bf16x8*)(kp + quad*8);
        bf16x8 kf1 = *(const bf16x8*)(kp + 32 + quad*8);
        const float bij = -sl2 * (kbase + (float)(j*16 + quad*4));
        #pragma unroll
        for (int i = 0; i < 2; ++i) {
          f32x4 t = {};
          t = __builtin_amdgcn_mfma_f32_16x16x32_bf16(kf0, qf[i][0], t, 0, 0, 0);
          t = __builtin_amdgcn_mfma_f32_16x16x32_bf16(kf1, qf[i][1], t, 0, 0, 0);
          float p0 = __builtin_amdgcn_exp2f(fmaf(t[0], c1, bij));
          float p1 = __builtin_amdgcn_exp2f(fmaf(t[1], c1, bij) - rs1);
          float p2 = __builtin_amdgcn_exp2f(fmaf(t[2], c1, bij) - rs2);
          float p3 = __builtin_amdgcn_exp2f(fmaf(t[3], c1, bij) - rs3);
          lsum[i] += (p0 + p1) + (p2 + p3);
          pw[i][jp][0] = pkbf(p0, p1);
          pw[i][jp][1] = pkbf(p2, p3);
        }
      }
      bf16x8 pb[2];
      #pragma unroll
      for (int i = 0; i < 2; ++i) {
        u32 fa0 = pw[i][0][0], fb0 = pw[i][1][0];
        u32 fa1 = pw[i][0][1], fb1 = pw[i][1][1];
        plswap(fa0, fb0);
        plswap(fa1, fb1);
        union { u32 u[4]; bf16x8 v; } fu;
        fu.u[0] = fa0; fu.u[1] = fa1; fu.u[2] = fb0; fu.u[3] = fb1;
        pb[i] = fu.v;
      }
      #pragma unroll
      for (int jn = 0; jn < 4; ++jn) {
        bf16x8 vf = *(const bf16x8*)&Vp[(long)(jn*16 + l16)*S_ + kt*128 + ks*32 + quad*8];
        o[0][jn] = __builtin_amdgcn_mfma_f32_16x16x32_bf16(vf, pb[0], o[0][jn], 0, 0, 0);
        o[1][jn] = __builtin_amdgcn_mfma_f32_16x16x32_bf16(vf, pb[1], o[1][jn], 0, 0, 0);
      }
    }
  }

  // -------- diagonal tile (kt == qt): masked, partial ks range --------
  {
    const int kt = qt;
    const int ksmax = w + 1;    // keys up to tile-local 32*w+31 = exactly ks pairs 0..w
    const u16* kts = Kp + (long)(kt*128 + l16)*P_;
    for (int ks = 0; ks < ksmax; ++ks) {
      u32 pw[2][2][2];
      #pragma unroll
      for (int jp = 0; jp < 2; ++jp) {
        const int j = 2*ks + jp;
        const u16* kp = kts + (long)(j*16)*P_;
        bf16x8 kf0 = *(const bf16x8*)(kp + quad*8);
        bf16x8 kf1 = *(const bf16x8*)(kp + 32 + quad*8);
        const int kl0 = j*16 + quad*4;  // tile-local key of r=0
        const float bij = -sl2 * (float)(kt*128 + kl0);
        #pragma unroll
        for (int i = 0; i < 2; ++i) {
          const int ql = w*32 + i*16 + l16;   // tile-local q row
          f32x4 t = {};
          t = __builtin_amdgcn_mfma_f32_16x16x32_bf16(kf0, qf[i][0], t, 0, 0, 0);
          t = __builtin_amdgcn_mfma_f32_16x16x32_bf16(kf1, qf[i][1], t, 0, 0, 0);
          float x0 = fmaf(t[0], c1, bij);
          float x1 = fmaf(t[1], c1, bij) - rs1;
          float x2 = fmaf(t[2], c1, bij) - rs2;
          float x3 = fmaf(t[3], c1, bij) - rs3;
          if (kl0 + 0 > ql) x0 = -1e30f;
          if (kl0 + 1 > ql) x1 = -1e30f;
          if (kl0 + 2 > ql) x2 = -1e30f;
          if (kl0 + 3 > ql) x3 = -1e30f;
          float p0 = __builtin_amdgcn_exp2f(x0);
          float p1 = __builtin_amdgcn_exp2f(x1);
          float p2 = __builtin_amdgcn_exp2f(x2);
          float p3 = __builtin_amdgcn_exp2f(x3);
          lsum[i] += (p0 + p1) + (p2 + p3);
          pw[i][jp][0] = pkbf(p0, p1);
          pw[i][jp][1] = pkbf(p2, p3);
        }
      }
      bf16x8 pb[2];
      #pragma unroll
      for (int i = 0; i < 2; ++i) {
        u32 fa0 = pw[i][0][0], fb0 = pw[i][1][0];
        u32 fa1 = pw[i][0][1], fb1 = pw[i][1][1];
        plswap(fa0, fb0);
        plswap(fa1, fb1);
        union { u32 u[4]; bf16x8 v; } fu;
        fu.u[0] = fa0; fu.u[1] = fa1; fu.u[2] = fb0; fu.u[3] = fb1;
        pb[i] = fu.v;
      }
      #pragma unroll
      for (int jn = 0; jn < 4; ++jn) {
        bf16x8 vf = *(const bf16x8*)&Vp[(long)(jn*16 + l16)*S_ + kt*128 + ks*32 + quad*8];
        o[0][jn] = __builtin_amdgcn_mfma_f32_16x16x32_bf16(vf, pb[0], o[0][jn], 0, 0, 0);
        o[1][jn] = __builtin_amdgcn_mfma_f32_16x16x32_bf16(vf, pb[1], o[1][jn], 0, 0, 0);
      }
    }
  }

  // -------- epilogue: reduce lsum across quads, scale, store (8B per lane-chunk) --------
  #pragma unroll
  for (int i = 0; i < 2; ++i) {
    lsum[i] += __shfl_xor(lsum[i], 16, 64);
    lsum[i] += __shfl_xor(lsum[i], 32, 64);
    const float inv = 1.0f / lsum[i];
    #pragma unroll
    for (int jn = 0; jn < 4; ++jn) {
      float v0 = o[i][jn][0] * inv, v1 = o[i][jn][1] * inv;
      float v2 = o[i][jn][2] * inv, v3 = o[i][jn][3] * inv;
      uint2 pk;
      pk.x = (u32)f2bf(v0) | ((u32)f2bf(v1) << 16);
      pk.y = (u32)f2bf(v2) | ((u32)f2bf(v3) << 16);
      *(uint2*)&Ob[((long)(b*S_ + q0 + i*16 + l16))*P_ + h*KD_ + jn*16 + quad*4] = pk;
    }
  }
}

extern "C" void kernel_launch(void* const* d_in, const int* in_sizes, int n_in,
                              void* d_out, int out_size, void* d_ws, size_t ws_size,
                              hipStream_t stream) {
  const float* q  = (const float*)d_in[0];
  const float* k  = (const float*)d_in[1];
  const float* v  = (const float*)d_in[2];
  const float* Wq = (const float*)d_in[3];
  const float* bq = (const float*)d_in[4];
  const float* Wk = (const float*)d_in[5];
  const float* bk = (const float*)d_in[6];
  const float* Wv = (const float*)d_in[7];
  const float* bv = (const float*)d_in[8];
  const float* Wo = (const float*)d_in[9];
  const float* bo = (const float*)d_in[10];

  const size_t X_ELEMS = (size_t)M_ * P_;
  const size_t W_ELEMS = (size_t)D_ * P_;
  u16* ws  = (u16*)d_ws;
  u16* Xq  = ws;
  u16* Xk  = Xq  + X_ELEMS;
  u16* Xv  = Xk  + X_ELEMS;
  u16* WqT = Xv  + X_ELEMS;
  u16* WkT = WqT + W_ELEMS;
  u16* WvT = WkT + W_ELEMS;
  u16* WoT = WvT + W_ELEMS;
  u16* Qb  = WoT + W_ELEMS;
  u16* Kb  = Qb  + X_ELEMS;
  u16* Vt  = Kb  + X_ELEMS;      // transposed V: [b][h][d][s]
  u16* Attn = Xq;                // reuse: Xq dead after projections

  cvt3_kernel<<<dim3((unsigned)(X_ELEMS/4/256), 3), 256, 0, stream>>>(q, k, v, Xq, Xk, Xv);

  transpose_cvt4<<<dim3(32, 32, 4), dim3(32, 8), 0, stream>>>(Wq, Wk, Wv, Wo,
                                                              WqT, WkT, WvT, WoT);

  gemm_qkv<<<dim3(M_/128, P_/128, 3), 256, 0, stream>>>(Xq, Xk, Xv, WqT, WkT, WvT,
                                                        bq, bk, bv, Qb, Kb, Vt);

  attn_kernel<<<dim3(1024), 256, 0, stream>>>(Qb, Kb, Vt, Attn);

  gemm_out<<<dim3(M_/128, P_/128), 256, 0, stream>>>(Attn, WoT, bo, (float*)d_out);
}

// Round 5
// 401.932 us; speedup vs baseline: 1.8401x; 1.8401x over previous
//
#include <hip/hip_runtime.h>

#define B_ 4
#define S_ 2048
#define D_ 1024
#define H_ 16
#define KD_ 64
#define P_ 1024
#define M_ (B_*S_)

typedef unsigned short u16;
typedef unsigned int u32;
typedef __attribute__((ext_vector_type(2))) unsigned u32x2;
typedef __attribute__((ext_vector_type(4))) float f32x4;
typedef __attribute__((ext_vector_type(8))) __bf16 bf16x8;

__device__ __forceinline__ u16 f2bf(float f) {
  u32 x = __float_as_uint(f);
  return (u16)((x + 0x7fffu + ((x >> 16) & 1u)) >> 16);
}

__device__ __forceinline__ void gl_lds16(const u16* g, u16* l) {
  __builtin_amdgcn_global_load_lds((__attribute__((address_space(1))) void*)g,
                                   (__attribute__((address_space(3))) void*)l, 16, 0, 0);
}

// pack bf16(b)<<16 | bf16(a), round-to-nearest (+0x8000 then take hi16 via v_perm)
__device__ __forceinline__ u32 pkbf(float a, float b) {
  return __builtin_amdgcn_perm(__float_as_uint(b) + 0x8000u,
                               __float_as_uint(a) + 0x8000u, 0x07060302u);
}

// Quad redistribution for P -> PV B-operand (proven in rounds 2-3).
// After this: a = [a@q0, a@q2, b@q0, b@q2], b = [a@q1, a@q3, b@q1, b@q3]
// (x@qN = value of x at source quad N, same l16).
#if __has_builtin(__builtin_amdgcn_permlane32_swap) && __has_builtin(__builtin_amdgcn_permlane16_swap)
__device__ __forceinline__ void plswap(u32& a, u32& b) {
  u32x2 r32 = __builtin_amdgcn_permlane32_swap(a, b, false, false);
  u32x2 r16 = __builtin_amdgcn_permlane16_swap(r32[0], r32[1], false, false);
  a = r16[0]; b = r16[1];
}
#else
__device__ __forceinline__ void plswap(u32& a, u32& b) {
  const int l = threadIdx.x & 63;
  const int quad = l >> 4, l16 = l & 15;
  int i0 = (((quad & 1) * 32) + l16) * 4;
  int i1 = i0 + 64;
  int a_lo = __builtin_amdgcn_ds_bpermute(i0, (int)a);
  int b_lo = __builtin_amdgcn_ds_bpermute(i0, (int)b);
  int a_hi = __builtin_amdgcn_ds_bpermute(i1, (int)a);
  int b_hi = __builtin_amdgcn_ds_bpermute(i1, (int)b);
  u32 na = (quad < 2) ? (u32)a_lo : (u32)b_lo;
  u32 nb = (quad < 2) ? (u32)a_hi : (u32)b_hi;
  a = na; b = nb;
}
#endif

// ---------------- fp32 -> bf16 convert, 3 tensors in one launch ----------------
__global__ void cvt3_kernel(const float* __restrict__ q, const float* __restrict__ k,
                            const float* __restrict__ v,
                            u16* __restrict__ Xq, u16* __restrict__ Xk, u16* __restrict__ Xv) {
  const int z = blockIdx.y;
  const float* in = z == 0 ? q : z == 1 ? k : v;
  u16* out = z == 0 ? Xq : z == 1 ? Xk : Xv;
  int i = blockIdx.x * 256 + threadIdx.x;
  float4 vv = ((const float4*)in)[i];
  ((u32*)out)[i*2+0] = (u32)f2bf(vv.x) | ((u32)f2bf(vv.y) << 16);
  ((u32*)out)[i*2+1] = (u32)f2bf(vv.z) | ((u32)f2bf(vv.w) << 16);
}

// ---------------- transpose 1024x1024 fp32 -> bf16 [C][R], 4 weights ----------------
__global__ void transpose_cvt4(const float* __restrict__ Wq, const float* __restrict__ Wk,
                               const float* __restrict__ Wv, const float* __restrict__ Wo,
                               u16* __restrict__ WqT, u16* __restrict__ WkT,
                               u16* __restrict__ WvT, u16* __restrict__ WoT) {
  const int z = blockIdx.z;
  const float* in = z == 0 ? Wq : z == 1 ? Wk : z == 2 ? Wv : Wo;
  u16* out = z == 0 ? WqT : z == 1 ? WkT : z == 2 ? WvT : WoT;
  __shared__ float tile[32][33];
  int bx = blockIdx.x * 32, by = blockIdx.y * 32;
  int tx = threadIdx.x, ty = threadIdx.y; // block (32,8)
  #pragma unroll
  for (int kk = 0; kk < 4; ++kk)
    tile[ty + kk*8][tx] = in[(by + ty + kk*8) * 1024 + bx + tx];
  __syncthreads();
  #pragma unroll
  for (int kk = 0; kk < 4; ++kk)
    out[(bx + ty + kk*8) * 1024 + by + tx] = f2bf(tile[tx][ty + kk*8]);
}

// ---------------- QKV projection GEMM (batched, z selects), m97 pattern ----------------
// z=0: Q -> Qb [row][P]; z=1: K -> Kb [row][P]; z=2: V -> Vt [b][h][d][s] (transposed!)
__global__ __launch_bounds__(256) void gemm_qkv(
    const u16* __restrict__ Xq, const u16* __restrict__ Xk, const u16* __restrict__ Xv,
    const u16* __restrict__ WqT, const u16* __restrict__ WkT, const u16* __restrict__ WvT,
    const float* __restrict__ bq, const float* __restrict__ bk, const float* __restrict__ bv,
    u16* __restrict__ Qb, u16* __restrict__ Kb, u16* __restrict__ Vt)
{
  constexpr int K = 1024, N = 1024, BK = 32;
  const int z = blockIdx.z;
  const u16* A  = z == 0 ? Xq  : z == 1 ? Xk  : Xv;
  const u16* Bt = z == 0 ? WqT : z == 1 ? WkT : WvT;
  const float* bias = z == 0 ? bq : z == 1 ? bk : bv;

  __shared__ alignas(16) u16 As[128*BK];
  __shared__ alignas(16) u16 Bs[128*BK];
  const int tid = threadIdx.x;
  const int w = tid >> 6, l = tid & 63;
  const int quad = l >> 4, l16 = l & 15;
  const int wm = (w >> 1) * 64, wn = (w & 1) * 64;
  const long mBase = (long)blockIdx.x * 128;
  const int  nBase = blockIdx.y * 128;

  f32x4 acc[4][4] = {};
  const int off0 = w*1024 + l*16;

  for (int kb = 0; kb < K/BK; ++kb) {
    __syncthreads();
    #pragma unroll
    for (int p = 0; p < 2; ++p) {
      int off = p*4096 + off0;
      int row = off >> 6;
      int cb  = off & 63;
      const u16* ga = A  + (mBase + row)*K + kb*BK + (cb >> 1);
      const u16* gb = Bt + ((long)(nBase + row))*K + kb*BK + (cb >> 1);
      gl_lds16(ga, (u16*)((char*)As + p*4096 + w*1024));
      gl_lds16(gb, (u16*)((char*)Bs + p*4096 + w*1024));
    }
    __syncthreads();
    bf16x8 af[4], bf[4];
    #pragma unroll
    for (int i = 0; i < 4; ++i) af[i] = *(const bf16x8*)&As[(wm + i*16 + l16)*BK + quad*8];
    #pragma unroll
    for (int j = 0; j < 4; ++j) bf[j] = *(const bf16x8*)&Bs[(wn + j*16 + l16)*BK + quad*8];
    #pragma unroll
    for (int i = 0; i < 4; ++i)
      #pragma unroll
      for (int j = 0; j < 4; ++j)
        acc[i][j] = __builtin_amdgcn_mfma_f32_16x16x32_bf16(af[i], bf[j], acc[i][j], 0, 0, 0);
  }

  if (z < 2) {
    u16* Cout = z == 0 ? Qb : Kb;
    #pragma unroll
    for (int i = 0; i < 4; ++i)
      #pragma unroll
      for (int j = 0; j < 4; ++j)
        #pragma unroll
        for (int r = 0; r < 4; ++r) {
          long row = mBase + wm + i*16 + quad*4 + r;
          int  col = nBase + wn + j*16 + l16;
          Cout[row*N + col] = f2bf(acc[i][j][r] + bias[col]);
        }
  } else {
    // V: write transposed per head: Vt[(b*1024 + h*64 + d)*2048 + s]; 4 consecutive s -> 8B stores
    #pragma unroll
    for (int i = 0; i < 4; ++i)
      #pragma unroll
      for (int j = 0; j < 4; ++j) {
        int  col  = nBase + wn + j*16 + l16;       // = h*64+d
        long row0 = mBase + wm + i*16 + quad*4;    // token; +r consecutive
        int  bb = (int)(row0 >> 11);
        int  ss = (int)(row0 & 2047);
        float bcol = bias[col];
        float v0 = acc[i][j][0] + bcol, v1 = acc[i][j][1] + bcol;
        float v2 = acc[i][j][2] + bcol, v3 = acc[i][j][3] + bcol;
        uint2 pk;
        pk.x = (u32)f2bf(v0) | ((u32)f2bf(v1) << 16);
        pk.y = (u32)f2bf(v2) | ((u32)f2bf(v3) << 16);
        *(uint2*)&Vt[((long)(bb*16) * 64 + col) * 2048 + ss] = pk;
      }
  }
}

// ---------------- output projection GEMM (fp32 out) ----------------
__global__ __launch_bounds__(256) void gemm_out(const u16* __restrict__ A,
                                                const u16* __restrict__ Bt,
                                                const float* __restrict__ bias,
                                                float* __restrict__ Cout)
{
  constexpr int K = 1024, N = 1024, BK = 32;
  __shared__ alignas(16) u16 As[128*BK];
  __shared__ alignas(16) u16 Bs[128*BK];
  const int tid = threadIdx.x;
  const int w = tid >> 6, l = tid & 63;
  const int quad = l >> 4, l16 = l & 15;
  const int wm = (w >> 1) * 64, wn = (w & 1) * 64;
  const long mBase = (long)blockIdx.x * 128;
  const int  nBase = blockIdx.y * 128;

  f32x4 acc[4][4] = {};
  const int off0 = w*1024 + l*16;

  for (int kb = 0; kb < K/BK; ++kb) {
    __syncthreads();
    #pragma unroll
    for (int p = 0; p < 2; ++p) {
      int off = p*4096 + off0;
      int row = off >> 6;
      int cb  = off & 63;
      const u16* ga = A  + (mBase + row)*K + kb*BK + (cb >> 1);
      const u16* gb = Bt + ((long)(nBase + row))*K + kb*BK + (cb >> 1);
      gl_lds16(ga, (u16*)((char*)As + p*4096 + w*1024));
      gl_lds16(gb, (u16*)((char*)Bs + p*4096 + w*1024));
    }
    __syncthreads();
    bf16x8 af[4], bf[4];
    #pragma unroll
    for (int i = 0; i < 4; ++i) af[i] = *(const bf16x8*)&As[(wm + i*16 + l16)*BK + quad*8];
    #pragma unroll
    for (int j = 0; j < 4; ++j) bf[j] = *(const bf16x8*)&Bs[(wn + j*16 + l16)*BK + quad*8];
    #pragma unroll
    for (int i = 0; i < 4; ++i)
      #pragma unroll
      for (int j = 0; j < 4; ++j)
        acc[i][j] = __builtin_amdgcn_mfma_f32_16x16x32_bf16(af[i], bf[j], acc[i][j], 0, 0, 0);
  }

  #pragma unroll
  for (int i = 0; i < 4; ++i)
    #pragma unroll
    for (int j = 0; j < 4; ++j)
      #pragma unroll
      for (int r = 0; r < 4; ++r) {
        long row = mBase + wm + i*16 + quad*4 + r;
        int  col = nBase + wn + j*16 + l16;
        Cout[row*N + col] = acc[i][j][r] + bias[col];
      }
}

// ---------------- flash attention: 4-wave blocks, register-only P (no LDS) ----------------
// grid 1024 = qtr(16, qt=15 first) x [b(4) x h(16)]; 256 threads = 4 waves.
// Wave w owns q sub-tile w*32 of the 128-q tile: per-wave geometry IDENTICAL to round 3.
// launch_bounds(256, 4): VGPR ceiling 128 — the kernel needs ~60-70; round 4's (256,8)
// capped at 64 and spilled to scratch (WRITE_SIZE 16MB -> 1.15GB, 3.8x slowdown).
// 4 blocks/CU resident (grid 1024 / 256 CU) = 16 waves/CU; 4 lockstep waves share
// K/V cache lines (K+V tile 32KB fits L1).
// S^T = K*Q^T (swapped operands): lane(quad,l16) reg r holds S^T[key=j*16+quad*4+r][q=l16].
// PV B-operand via pure quad permutation (plswap pairs) — no LDS, no barriers, no lgkm waits.
// Static-shift softmax: exponent = c1*s - sl2*k (ALiBi grows toward k=0), bounded;
// no max-tracking, no rescale; distant-key underflow to 0 is exact.
__global__ __launch_bounds__(256, 4) void attn_kernel(const u16* __restrict__ Qb,
                                                      const u16* __restrict__ Kb,
                                                      const u16* __restrict__ Vt,
                                                      u16* __restrict__ Ob)
{
  const int n = blockIdx.x;
  const int qt = 15 - (n >> 6);
  const int r6 = n & 63;
  const int b = r6 >> 4, h = r6 & 15;
  const int w = threadIdx.x >> 6;
  const int l = threadIdx.x & 63;
  const int quad = l >> 4, l16 = l & 15;
  const float LOG2E = 1.44269504089f;
  const float slope = exp2f(-0.5f * (float)(h + 1));
  const float c1  = 0.125f * LOG2E;
  const float sl2 = slope * LOG2E;
  const float rs1 = sl2, rs2 = 2.f*sl2, rs3 = 3.f*sl2;

  const int q0 = qt*128 + w*32;
  const u16* Qp = Qb + ((long)(b*S_ + q0))*P_ + h*KD_;
  const u16* Kp = Kb + ((long)(b*S_))*P_ + h*KD_;
  const u16* Vp = Vt + ((long)(b*H_ + h))*KD_*S_;

  // Q fragments (MFMA B-operand for S^T = K*Q^T)
  bf16x8 qf[2][2];
  #pragma unroll
  for (int i = 0; i < 2; ++i)
    #pragma unroll
    for (int kk = 0; kk < 2; ++kk)
      qf[i][kk] = *(const bf16x8*)&Qp[(long)(i*16 + l16)*P_ + kk*32 + quad*8];

  f32x4 o[2][4] = {};           // O^T accumulators: rows d (jn*16+quad*4+r), cols q=l16
  float lsum[2] = {0.f, 0.f};

  // -------- full (non-diagonal) key tiles --------
  for (int kt = 0; kt < qt; ++kt) {
    const u16* kts = Kp + (long)(kt*128 + l16)*P_;
    const float kbase = (float)(kt*128);
    #pragma unroll
    for (int ks = 0; ks < 4; ++ks) {
      u32 pw[2][2][2];          // [i][jp][c]
      #pragma unroll
      for (int jp = 0; jp < 2; ++jp) {
        const int j = 2*ks + jp;
        const u16* kp = kts + (long)(j*16)*P_;
        bf16x8 kf0 = *(const bf16x8*)(kp + quad*8);
        bf16x8 kf1 = *(const bf16x8*)(kp + 32 + quad*8);
        const float bij = -sl2 * (kbase + (float)(j*16 + quad*4));
        #pragma unroll
        for (int i = 0; i < 2; ++i) {
          f32x4 t = {};
          t = __builtin_amdgcn_mfma_f32_16x16x32_bf16(kf0, qf[i][0], t, 0, 0, 0);
          t = __builtin_amdgcn_mfma_f32_16x16x32_bf16(kf1, qf[i][1], t, 0, 0, 0);
          float p0 = __builtin_amdgcn_exp2f(fmaf(t[0], c1, bij));
          float p1 = __builtin_amdgcn_exp2f(fmaf(t[1], c1, bij) - rs1);
          float p2 = __builtin_amdgcn_exp2f(fmaf(t[2], c1, bij) - rs2);
          float p3 = __builtin_amdgcn_exp2f(fmaf(t[3], c1, bij) - rs3);
          lsum[i] += (p0 + p1) + (p2 + p3);
          pw[i][jp][0] = pkbf(p0, p1);
          pw[i][jp][1] = pkbf(p2, p3);
        }
      }
      bf16x8 pb[2];
      #pragma unroll
      for (int i = 0; i < 2; ++i) {
        u32 fa0 = pw[i][0][0], fb0 = pw[i][1][0];
        u32 fa1 = pw[i][0][1], fb1 = pw[i][1][1];
        plswap(fa0, fb0);
        plswap(fa1, fb1);
        union { u32 u[4]; bf16x8 v; } fu;
        fu.u[0] = fa0; fu.u[1] = fa1; fu.u[2] = fb0; fu.u[3] = fb1;
        pb[i] = fu.v;
      }
      #pragma unroll
      for (int jn = 0; jn < 4; ++jn) {
        bf16x8 vf = *(const bf16x8*)&Vp[(long)(jn*16 + l16)*S_ + kt*128 + ks*32 + quad*8];
        o[0][jn] = __builtin_amdgcn_mfma_f32_16x16x32_bf16(vf, pb[0], o[0][jn], 0, 0, 0);
        o[1][jn] = __builtin_amdgcn_mfma_f32_16x16x32_bf16(vf, pb[1], o[1][jn], 0, 0, 0);
      }
    }
  }

  // -------- diagonal tile (kt == qt): masked, partial ks range --------
  {
    const int kt = qt;
    const int ksmax = w + 1;    // keys up to tile-local 32*w+31 = exactly ks pairs 0..w
    const u16* kts = Kp + (long)(kt*128 + l16)*P_;
    for (int ks = 0; ks < ksmax; ++ks) {
      u32 pw[2][2][2];
      #pragma unroll
      for (int jp = 0; jp < 2; ++jp) {
        const int j = 2*ks + jp;
        const u16* kp = kts + (long)(j*16)*P_;
        bf16x8 kf0 = *(const bf16x8*)(kp + quad*8);
        bf16x8 kf1 = *(const bf16x8*)(kp + 32 + quad*8);
        const int kl0 = j*16 + quad*4;  // tile-local key of r=0
        const float bij = -sl2 * (float)(kt*128 + kl0);
        #pragma unroll
        for (int i = 0; i < 2; ++i) {
          const int ql = w*32 + i*16 + l16;   // tile-local q row
          f32x4 t = {};
          t = __builtin_amdgcn_mfma_f32_16x16x32_bf16(kf0, qf[i][0], t, 0, 0, 0);
          t = __builtin_amdgcn_mfma_f32_16x16x32_bf16(kf1, qf[i][1], t, 0, 0, 0);
          float x0 = fmaf(t[0], c1, bij);
          float x1 = fmaf(t[1], c1, bij) - rs1;
          float x2 = fmaf(t[2], c1, bij) - rs2;
          float x3 = fmaf(t[3], c1, bij) - rs3;
          if (kl0 + 0 > ql) x0 = -1e30f;
          if (kl0 + 1 > ql) x1 = -1e30f;
          if (kl0 + 2 > ql) x2 = -1e30f;
          if (kl0 + 3 > ql) x3 = -1e30f;
          float p0 = __builtin_amdgcn_exp2f(x0);
          float p1 = __builtin_amdgcn_exp2f(x1);
          float p2 = __builtin_amdgcn_exp2f(x2);
          float p3 = __builtin_amdgcn_exp2f(x3);
          lsum[i] += (p0 + p1) + (p2 + p3);
          pw[i][jp][0] = pkbf(p0, p1);
          pw[i][jp][1] = pkbf(p2, p3);
        }
      }
      bf16x8 pb[2];
      #pragma unroll
      for (int i = 0; i < 2; ++i) {
        u32 fa0 = pw[i][0][0], fb0 = pw[i][1][0];
        u32 fa1 = pw[i][0][1], fb1 = pw[i][1][1];
        plswap(fa0, fb0);
        plswap(fa1, fb1);
        union { u32 u[4]; bf16x8 v; } fu;
        fu.u[0] = fa0; fu.u[1] = fa1; fu.u[2] = fb0; fu.u[3] = fb1;
        pb[i] = fu.v;
      }
      #pragma unroll
      for (int jn = 0; jn < 4; ++jn) {
        bf16x8 vf = *(const bf16x8*)&Vp[(long)(jn*16 + l16)*S_ + kt*128 + ks*32 + quad*8];
        o[0][jn] = __builtin_amdgcn_mfma_f32_16x16x32_bf16(vf, pb[0], o[0][jn], 0, 0, 0);
        o[1][jn] = __builtin_amdgcn_mfma_f32_16x16x32_bf16(vf, pb[1], o[1][jn], 0, 0, 0);
      }
    }
  }

  // -------- epilogue: reduce lsum across quads, scale, store (8B per lane-chunk) --------
  #pragma unroll
  for (int i = 0; i < 2; ++i) {
    lsum[i] += __shfl_xor(lsum[i], 16, 64);
    lsum[i] += __shfl_xor(lsum[i], 32, 64);
    const float inv = 1.0f / lsum[i];
    #pragma unroll
    for (int jn = 0; jn < 4; ++jn) {
      float v0 = o[i][jn][0] * inv, v1 = o[i][jn][1] * inv;
      float v2 = o[i][jn][2] * inv, v3 = o[i][jn][3] * inv;
      uint2 pk;
      pk.x = (u32)f2bf(v0) | ((u32)f2bf(v1) << 16);
      pk.y = (u32)f2bf(v2) | ((u32)f2bf(v3) << 16);
      *(uint2*)&Ob[((long)(b*S_ + q0 + i*16 + l16))*P_ + h*KD_ + jn*16 + quad*4] = pk;
    }
  }
}

extern "C" void kernel_launch(void* const* d_in, const int* in_sizes, int n_in,
                              void* d_out, int out_size, void* d_ws, size_t ws_size,
                              hipStream_t stream) {
  const float* q  = (const float*)d_in[0];
  const float* k  = (const float*)d_in[1];
  const float* v  = (const float*)d_in[2];
  const float* Wq = (const float*)d_in[3];
  const float* bq = (const float*)d_in[4];
  const float* Wk = (const float*)d_in[5];
  const float* bk = (const float*)d_in[6];
  const float* Wv = (const float*)d_in[7];
  const float* bv = (const float*)d_in[8];
  const float* Wo = (const float*)d_in[9];
  const float* bo = (const float*)d_in[10];

  const size_t X_ELEMS = (size_t)M_ * P_;
  const size_t W_ELEMS = (size_t)D_ * P_;
  u16* ws  = (u16*)d_ws;
  u16* Xq  = ws;
  u16* Xk  = Xq  + X_ELEMS;
  u16* Xv  = Xk  + X_ELEMS;
  u16* WqT = Xv  + X_ELEMS;
  u16* WkT = WqT + W_ELEMS;
  u16* WvT = WkT + W_ELEMS;
  u16* WoT = WvT + W_ELEMS;
  u16* Qb  = WoT + W_ELEMS;
  u16* Kb  = Qb  + X_ELEMS;
  u16* Vt  = Kb  + X_ELEMS;      // transposed V: [b][h][d][s]
  u16* Attn = Xq;                // reuse: Xq dead after projections

  cvt3_kernel<<<dim3((unsigned)(X_ELEMS/4/256), 3), 256, 0, stream>>>(q, k, v, Xq, Xk, Xv);

  transpose_cvt4<<<dim3(32, 32, 4), dim3(32, 8), 0, stream>>>(Wq, Wk, Wv, Wo,
                                                              WqT, WkT, WvT, WoT);

  gemm_qkv<<<dim3(M_/128, P_/128, 3), 256, 0, stream>>>(Xq, Xk, Xv, WqT, WkT, WvT,
                                                        bq, bk, bv, Qb, Kb, Vt);

  attn_kernel<<<dim3(1024), 256, 0, stream>>>(Qb, Kb, Vt, Attn);

  gemm_out<<<dim3(M_/128, P_/128), 256, 0, stream>>>(Attn, WoT, bo, (float*)d_out);
}

// Round 6
// 381.178 us; speedup vs baseline: 1.9403x; 1.0544x over previous
//
#include <hip/hip_runtime.h>

#define B_ 4
#define S_ 2048
#define D_ 1024
#define H_ 16
#define KD_ 64
#define P_ 1024
#define M_ (B_*S_)

typedef unsigned short u16;
typedef unsigned int u32;
typedef __attribute__((ext_vector_type(2))) unsigned u32x2;
typedef __attribute__((ext_vector_type(4))) float f32x4;
typedef __attribute__((ext_vector_type(8))) __bf16 bf16x8;

__device__ __forceinline__ u16 f2bf(float f) {
  u32 x = __float_as_uint(f);
  return (u16)((x + 0x7fffu + ((x >> 16) & 1u)) >> 16);
}

__device__ __forceinline__ void gl_lds16(const u16* g, u16* l) {
  __builtin_amdgcn_global_load_lds((__attribute__((address_space(1))) void*)g,
                                   (__attribute__((address_space(3))) void*)l, 16, 0, 0);
}

// pack bf16(b)<<16 | bf16(a), round-to-nearest (+0x8000 then take hi16 via v_perm)
__device__ __forceinline__ u32 pkbf(float a, float b) {
  return __builtin_amdgcn_perm(__float_as_uint(b) + 0x8000u,
                               __float_as_uint(a) + 0x8000u, 0x07060302u);
}

// Quad redistribution for P -> PV B-operand (proven in rounds 2-5).
// After this: a = [a@q0, a@q2, b@q0, b@q2], b = [a@q1, a@q3, b@q1, b@q3]
// (x@qN = value of x at source quad N, same l16).
#if __has_builtin(__builtin_amdgcn_permlane32_swap) && __has_builtin(__builtin_amdgcn_permlane16_swap)
__device__ __forceinline__ void plswap(u32& a, u32& b) {
  u32x2 r32 = __builtin_amdgcn_permlane32_swap(a, b, false, false);
  u32x2 r16 = __builtin_amdgcn_permlane16_swap(r32[0], r32[1], false, false);
  a = r16[0]; b = r16[1];
}
#else
__device__ __forceinline__ void plswap(u32& a, u32& b) {
  const int l = threadIdx.x & 63;
  const int quad = l >> 4, l16 = l & 15;
  int i0 = (((quad & 1) * 32) + l16) * 4;
  int i1 = i0 + 64;
  int a_lo = __builtin_amdgcn_ds_bpermute(i0, (int)a);
  int b_lo = __builtin_amdgcn_ds_bpermute(i0, (int)b);
  int a_hi = __builtin_amdgcn_ds_bpermute(i1, (int)a);
  int b_hi = __builtin_amdgcn_ds_bpermute(i1, (int)b);
  u32 na = (quad < 2) ? (u32)a_lo : (u32)b_lo;
  u32 nb = (quad < 2) ? (u32)a_hi : (u32)b_hi;
  a = na; b = nb;
}
#endif

// ---------------- fp32 -> bf16 convert, 3 tensors in one launch ----------------
__global__ void cvt3_kernel(const float* __restrict__ q, const float* __restrict__ k,
                            const float* __restrict__ v,
                            u16* __restrict__ Xq, u16* __restrict__ Xk, u16* __restrict__ Xv) {
  const int z = blockIdx.y;
  const float* in = z == 0 ? q : z == 1 ? k : v;
  u16* out = z == 0 ? Xq : z == 1 ? Xk : Xv;
  int i = blockIdx.x * 256 + threadIdx.x;
  float4 vv = ((const float4*)in)[i];
  ((u32*)out)[i*2+0] = (u32)f2bf(vv.x) | ((u32)f2bf(vv.y) << 16);
  ((u32*)out)[i*2+1] = (u32)f2bf(vv.z) | ((u32)f2bf(vv.w) << 16);
}

// ---------------- transpose 1024x1024 fp32 -> bf16 [C][R], 4 weights ----------------
__global__ void transpose_cvt4(const float* __restrict__ Wq, const float* __restrict__ Wk,
                               const float* __restrict__ Wv, const float* __restrict__ Wo,
                               u16* __restrict__ WqT, u16* __restrict__ WkT,
                               u16* __restrict__ WvT, u16* __restrict__ WoT) {
  const int z = blockIdx.z;
  const float* in = z == 0 ? Wq : z == 1 ? Wk : z == 2 ? Wv : Wo;
  u16* out = z == 0 ? WqT : z == 1 ? WkT : z == 2 ? WvT : WoT;
  __shared__ float tile[32][33];
  int bx = blockIdx.x * 32, by = blockIdx.y * 32;
  int tx = threadIdx.x, ty = threadIdx.y; // block (32,8)
  #pragma unroll
  for (int kk = 0; kk < 4; ++kk)
    tile[ty + kk*8][tx] = in[(by + ty + kk*8) * 1024 + bx + tx];
  __syncthreads();
  #pragma unroll
  for (int kk = 0; kk < 4; ++kk)
    out[(bx + ty + kk*8) * 1024 + by + tx] = f2bf(tile[tx][ty + kk*8]);
}

// ---------------- QKV projection GEMM (batched, z selects), m97 pattern ----------------
// z=0: Q -> Qb [row][P]; z=1: K -> Kb [row][P]; z=2: V -> Vt [b][h][d][s] (transposed!)
__global__ __launch_bounds__(256) void gemm_qkv(
    const u16* __restrict__ Xq, const u16* __restrict__ Xk, const u16* __restrict__ Xv,
    const u16* __restrict__ WqT, const u16* __restrict__ WkT, const u16* __restrict__ WvT,
    const float* __restrict__ bq, const float* __restrict__ bk, const float* __restrict__ bv,
    u16* __restrict__ Qb, u16* __restrict__ Kb, u16* __restrict__ Vt)
{
  constexpr int K = 1024, N = 1024, BK = 32;
  const int z = blockIdx.z;
  const u16* A  = z == 0 ? Xq  : z == 1 ? Xk  : Xv;
  const u16* Bt = z == 0 ? WqT : z == 1 ? WkT : WvT;
  const float* bias = z == 0 ? bq : z == 1 ? bk : bv;

  __shared__ alignas(16) u16 As[128*BK];
  __shared__ alignas(16) u16 Bs[128*BK];
  const int tid = threadIdx.x;
  const int w = tid >> 6, l = tid & 63;
  const int quad = l >> 4, l16 = l & 15;
  const int wm = (w >> 1) * 64, wn = (w & 1) * 64;
  const long mBase = (long)blockIdx.x * 128;
  const int  nBase = blockIdx.y * 128;

  f32x4 acc[4][4] = {};
  const int off0 = w*1024 + l*16;

  for (int kb = 0; kb < K/BK; ++kb) {
    __syncthreads();
    #pragma unroll
    for (int p = 0; p < 2; ++p) {
      int off = p*4096 + off0;
      int row = off >> 6;
      int cb  = off & 63;
      const u16* ga = A  + (mBase + row)*K + kb*BK + (cb >> 1);
      const u16* gb = Bt + ((long)(nBase + row))*K + kb*BK + (cb >> 1);
      gl_lds16(ga, (u16*)((char*)As + p*4096 + w*1024));
      gl_lds16(gb, (u16*)((char*)Bs + p*4096 + w*1024));
    }
    __syncthreads();
    bf16x8 af[4], bf[4];
    #pragma unroll
    for (int i = 0; i < 4; ++i) af[i] = *(const bf16x8*)&As[(wm + i*16 + l16)*BK + quad*8];
    #pragma unroll
    for (int j = 0; j < 4; ++j) bf[j] = *(const bf16x8*)&Bs[(wn + j*16 + l16)*BK + quad*8];
    #pragma unroll
    for (int i = 0; i < 4; ++i)
      #pragma unroll
      for (int j = 0; j < 4; ++j)
        acc[i][j] = __builtin_amdgcn_mfma_f32_16x16x32_bf16(af[i], bf[j], acc[i][j], 0, 0, 0);
  }

  if (z < 2) {
    u16* Cout = z == 0 ? Qb : Kb;
    #pragma unroll
    for (int i = 0; i < 4; ++i)
      #pragma unroll
      for (int j = 0; j < 4; ++j)
        #pragma unroll
        for (int r = 0; r < 4; ++r) {
          long row = mBase + wm + i*16 + quad*4 + r;
          int  col = nBase + wn + j*16 + l16;
          Cout[row*N + col] = f2bf(acc[i][j][r] + bias[col]);
        }
  } else {
    // V: write transposed per head: Vt[(b*1024 + h*64 + d)*2048 + s]; 4 consecutive s -> 8B stores
    #pragma unroll
    for (int i = 0; i < 4; ++i)
      #pragma unroll
      for (int j = 0; j < 4; ++j) {
        int  col  = nBase + wn + j*16 + l16;       // = h*64+d
        long row0 = mBase + wm + i*16 + quad*4;    // token; +r consecutive
        int  bb = (int)(row0 >> 11);
        int  ss = (int)(row0 & 2047);
        float bcol = bias[col];
        float v0 = acc[i][j][0] + bcol, v1 = acc[i][j][1] + bcol;
        float v2 = acc[i][j][2] + bcol, v3 = acc[i][j][3] + bcol;
        uint2 pk;
        pk.x = (u32)f2bf(v0) | ((u32)f2bf(v1) << 16);
        pk.y = (u32)f2bf(v2) | ((u32)f2bf(v3) << 16);
        *(uint2*)&Vt[((long)(bb*16) * 64 + col) * 2048 + ss] = pk;
      }
  }
}

// ---------------- output projection GEMM (fp32 out) ----------------
__global__ __launch_bounds__(256) void gemm_out(const u16* __restrict__ A,
                                                const u16* __restrict__ Bt,
                                                const float* __restrict__ bias,
                                                float* __restrict__ Cout)
{
  constexpr int K = 1024, N = 1024, BK = 32;
  __shared__ alignas(16) u16 As[128*BK];
  __shared__ alignas(16) u16 Bs[128*BK];
  const int tid = threadIdx.x;
  const int w = tid >> 6, l = tid & 63;
  const int quad = l >> 4, l16 = l & 15;
  const int wm = (w >> 1) * 64, wn = (w & 1) * 64;
  const long mBase = (long)blockIdx.x * 128;
  const int  nBase = blockIdx.y * 128;

  f32x4 acc[4][4] = {};
  const int off0 = w*1024 + l*16;

  for (int kb = 0; kb < K/BK; ++kb) {
    __syncthreads();
    #pragma unroll
    for (int p = 0; p < 2; ++p) {
      int off = p*4096 + off0;
      int row = off >> 6;
      int cb  = off & 63;
      const u16* ga = A  + (mBase + row)*K + kb*BK + (cb >> 1);
      const u16* gb = Bt + ((long)(nBase + row))*K + kb*BK + (cb >> 1);
      gl_lds16(ga, (u16*)((char*)As + p*4096 + w*1024));
      gl_lds16(gb, (u16*)((char*)Bs + p*4096 + w*1024));
    }
    __syncthreads();
    bf16x8 af[4], bf[4];
    #pragma unroll
    for (int i = 0; i < 4; ++i) af[i] = *(const bf16x8*)&As[(wm + i*16 + l16)*BK + quad*8];
    #pragma unroll
    for (int j = 0; j < 4; ++j) bf[j] = *(const bf16x8*)&Bs[(wn + j*16 + l16)*BK + quad*8];
    #pragma unroll
    for (int i = 0; i < 4; ++i)
      #pragma unroll
      for (int j = 0; j < 4; ++j)
        acc[i][j] = __builtin_amdgcn_mfma_f32_16x16x32_bf16(af[i], bf[j], acc[i][j], 0, 0, 0);
  }

  #pragma unroll
  for (int i = 0; i < 4; ++i)
    #pragma unroll
    for (int j = 0; j < 4; ++j)
      #pragma unroll
      for (int r = 0; r < 4; ++r) {
        long row = mBase + wm + i*16 + quad*4 + r;
        int  col = nBase + wn + j*16 + l16;
        Cout[row*N + col] = acc[i][j][r] + bias[col];
      }
}

// ---------------- flash attention: qt-paired blocks + register double-buffered K/V ------
// grid 512 = pair(8) x [b(4) x h(16)]; 256 threads = 4 waves. Block handles TWO q-tiles:
// qt = 15-pairIdx then qt = pairIdx -> every block does exactly 17 tile-units (balanced;
// round-5 showed dur was set by worst-CU critical path, not throughput).
// Main loop software-pipelined at depth 1: iteration it's 8 loads (4 K + 4 V bf16x8)
// issue into buffer B while computing iteration it-1 from buffer A (named regs, static
// indexing) -> load latency hides under ~350cy of MFMA/exp compute. launch_bounds(256,2)
// gives a 256-VGPR ceiling: no spill possible (round-4 lesson; round-5's 56 VGPR forced
// register recycling = serialized loads, ~25K cy/pass measured).
// S^T = K*Q^T; PV B-operand via plswap quad permutation. Static-shift softmax.
__global__ __launch_bounds__(256, 2) void attn_kernel(const u16* __restrict__ Qb,
                                                      const u16* __restrict__ Kb,
                                                      const u16* __restrict__ Vt,
                                                      u16* __restrict__ Ob)
{
  const int n = blockIdx.x;
  const int pairIdx = n >> 6;            // 0..7
  const int r6 = n & 63;
  const int b = r6 >> 4, h = r6 & 15;
  const int w = threadIdx.x >> 6;
  const int l = threadIdx.x & 63;
  const int quad = l >> 4, l16 = l & 15;
  const float LOG2E = 1.44269504089f;
  const float slope = exp2f(-0.5f * (float)(h + 1));
  const float c1  = 0.125f * LOG2E;
  const float sl2 = slope * LOG2E;
  const float rs1 = sl2, rs2 = 2.f*sl2, rs3 = 3.f*sl2;

  const u16* Kp = Kb + ((long)(b*S_))*P_ + h*KD_;
  const u16* Vp = Vt + ((long)(b*H_ + h))*KD_*S_;

  for (int half = 0; half < 2; ++half) {
    const int qt = half == 0 ? (15 - pairIdx) : pairIdx;
    const int q0 = qt*128 + w*32;
    const u16* Qp = Qb + ((long)(b*S_ + q0))*P_ + h*KD_;

    // Q fragments (MFMA B-operand for S^T = K*Q^T)
    bf16x8 qf[2][2];
    #pragma unroll
    for (int i = 0; i < 2; ++i)
      #pragma unroll
      for (int kk = 0; kk < 2; ++kk)
        qf[i][kk] = *(const bf16x8*)&Qp[(long)(i*16 + l16)*P_ + kk*32 + quad*8];

    f32x4 o[2][4] = {};         // O^T accumulators: rows d (jn*16+quad*4+r), cols q=l16
    float lsum[2] = {0.f, 0.f};

    // -------- pipelined full (non-diagonal) key tiles: it = kt*4 + ks --------
    auto issue = [&](int it, bf16x8& k00, bf16x8& k01, bf16x8& k10, bf16x8& k11,
                     bf16x8& v0, bf16x8& v1, bf16x8& v2, bf16x8& v3) {
      const int kt = it >> 2, ks = it & 3;
      const u16* kp = Kp + (long)(kt*128 + l16 + 2*ks*16)*P_;
      k00 = *(const bf16x8*)(kp + quad*8);
      k01 = *(const bf16x8*)(kp + 32 + quad*8);
      k10 = *(const bf16x8*)(kp + 16*P_ + quad*8);
      k11 = *(const bf16x8*)(kp + 16*P_ + 32 + quad*8);
      const u16* vp = Vp + (long)l16*S_ + kt*128 + ks*32 + quad*8;
      v0 = *(const bf16x8*)(vp);
      v1 = *(const bf16x8*)(vp + 16*S_);
      v2 = *(const bf16x8*)(vp + 32*S_);
      v3 = *(const bf16x8*)(vp + 48*S_);
    };
    auto compute = [&](int it, const bf16x8& k00, const bf16x8& k01,
                       const bf16x8& k10, const bf16x8& k11,
                       const bf16x8& v0, const bf16x8& v1,
                       const bf16x8& v2, const bf16x8& v3) {
      const int kt = it >> 2, ks = it & 3;
      const float kb0 = (float)(kt*128 + 2*ks*16 + quad*4);
      u32 pw0[2][2], pw1[2][2];          // [i][c] for jp=0 / jp=1
      {
        const float bij = -sl2 * kb0;
        #pragma unroll
        for (int i = 0; i < 2; ++i) {
          f32x4 t = {};
          t = __builtin_amdgcn_mfma_f32_16x16x32_bf16(k00, qf[i][0], t, 0, 0, 0);
          t = __builtin_amdgcn_mfma_f32_16x16x32_bf16(k01, qf[i][1], t, 0, 0, 0);
          float p0 = __builtin_amdgcn_exp2f(fmaf(t[0], c1, bij));
          float p1 = __builtin_amdgcn_exp2f(fmaf(t[1], c1, bij) - rs1);
          float p2 = __builtin_amdgcn_exp2f(fmaf(t[2], c1, bij) - rs2);
          float p3 = __builtin_amdgcn_exp2f(fmaf(t[3], c1, bij) - rs3);
          lsum[i] += (p0 + p1) + (p2 + p3);
          pw0[i][0] = pkbf(p0, p1);
          pw0[i][1] = pkbf(p2, p3);
        }
      }
      {
        const float bij = -sl2 * (kb0 + 16.f);
        #pragma unroll
        for (int i = 0; i < 2; ++i) {
          f32x4 t = {};
          t = __builtin_amdgcn_mfma_f32_16x16x32_bf16(k10, qf[i][0], t, 0, 0, 0);
          t = __builtin_amdgcn_mfma_f32_16x16x32_bf16(k11, qf[i][1], t, 0, 0, 0);
          float p0 = __builtin_amdgcn_exp2f(fmaf(t[0], c1, bij));
          float p1 = __builtin_amdgcn_exp2f(fmaf(t[1], c1, bij) - rs1);
          float p2 = __builtin_amdgcn_exp2f(fmaf(t[2], c1, bij) - rs2);
          float p3 = __builtin_amdgcn_exp2f(fmaf(t[3], c1, bij) - rs3);
          lsum[i] += (p0 + p1) + (p2 + p3);
          pw1[i][0] = pkbf(p0, p1);
          pw1[i][1] = pkbf(p2, p3);
        }
      }
      bf16x8 pb[2];
      #pragma unroll
      for (int i = 0; i < 2; ++i) {
        u32 fa0 = pw0[i][0], fb0 = pw1[i][0];
        u32 fa1 = pw0[i][1], fb1 = pw1[i][1];
        plswap(fa0, fb0);
        plswap(fa1, fb1);
        union { u32 u[4]; bf16x8 v; } fu;
        fu.u[0] = fa0; fu.u[1] = fa1; fu.u[2] = fb0; fu.u[3] = fb1;
        pb[i] = fu.v;
      }
      o[0][0] = __builtin_amdgcn_mfma_f32_16x16x32_bf16(v0, pb[0], o[0][0], 0, 0, 0);
      o[1][0] = __builtin_amdgcn_mfma_f32_16x16x32_bf16(v0, pb[1], o[1][0], 0, 0, 0);
      o[0][1] = __builtin_amdgcn_mfma_f32_16x16x32_bf16(v1, pb[0], o[0][1], 0, 0, 0);
      o[1][1] = __builtin_amdgcn_mfma_f32_16x16x32_bf16(v1, pb[1], o[1][1], 0, 0, 0);
      o[0][2] = __builtin_amdgcn_mfma_f32_16x16x32_bf16(v2, pb[0], o[0][2], 0, 0, 0);
      o[1][2] = __builtin_amdgcn_mfma_f32_16x16x32_bf16(v2, pb[1], o[1][2], 0, 0, 0);
      o[0][3] = __builtin_amdgcn_mfma_f32_16x16x32_bf16(v3, pb[0], o[0][3], 0, 0, 0);
      o[1][3] = __builtin_amdgcn_mfma_f32_16x16x32_bf16(v3, pb[1], o[1][3], 0, 0, 0);
    };

    const int nit = qt * 4;
    if (nit > 0) {
      bf16x8 ak00, ak01, ak10, ak11, av0, av1, av2, av3;   // buffer A
      bf16x8 bk00, bk01, bk10, bk11, bv0, bv1, bv2, bv3;   // buffer B
      issue(0, ak00, ak01, ak10, ak11, av0, av1, av2, av3);
      int it = 0;
      while (true) {
        if (it + 1 < nit) issue(it + 1, bk00, bk01, bk10, bk11, bv0, bv1, bv2, bv3);
        compute(it, ak00, ak01, ak10, ak11, av0, av1, av2, av3);
        ++it; if (it == nit) break;
        if (it + 1 < nit) issue(it + 1, ak00, ak01, ak10, ak11, av0, av1, av2, av3);
        compute(it, bk00, bk01, bk10, bk11, bv0, bv1, bv2, bv3);
        ++it; if (it == nit) break;
      }
    }

    // -------- diagonal tile (kt == qt): masked, partial ks range --------
    {
      const int kt = qt;
      const int ksmax = w + 1;  // keys up to tile-local 32*w+31 = exactly ks pairs 0..w
      const u16* kts = Kp + (long)(kt*128 + l16)*P_;
      for (int ks = 0; ks < ksmax; ++ks) {
        u32 pw[2][2][2];
        #pragma unroll
        for (int jp = 0; jp < 2; ++jp) {
          const int j = 2*ks + jp;
          const u16* kp = kts + (long)(j*16)*P_;
          bf16x8 kf0 = *(const bf16x8*)(kp + quad*8);
          bf16x8 kf1 = *(const bf16x8*)(kp + 32 + quad*8);
          const int kl0 = j*16 + quad*4;  // tile-local key of r=0
          const float bij = -sl2 * (float)(kt*128 + kl0);
          #pragma unroll
          for (int i = 0; i < 2; ++i) {
            const int ql = w*32 + i*16 + l16;   // tile-local q row
            f32x4 t = {};
            t = __builtin_amdgcn_mfma_f32_16x16x32_bf16(kf0, qf[i][0], t, 0, 0, 0);
            t = __builtin_amdgcn_mfma_f32_16x16x32_bf16(kf1, qf[i][1], t, 0, 0, 0);
            float x0 = fmaf(t[0], c1, bij);
            float x1 = fmaf(t[1], c1, bij) - rs1;
            float x2 = fmaf(t[2], c1, bij) - rs2;
            float x3 = fmaf(t[3], c1, bij) - rs3;
            if (kl0 + 0 > ql) x0 = -1e30f;
            if (kl0 + 1 > ql) x1 = -1e30f;
            if (kl0 + 2 > ql) x2 = -1e30f;
            if (kl0 + 3 > ql) x3 = -1e30f;
            float p0 = __builtin_amdgcn_exp2f(x0);
            float p1 = __builtin_amdgcn_exp2f(x1);
            float p2 = __builtin_amdgcn_exp2f(x2);
            float p3 = __builtin_amdgcn_exp2f(x3);
            lsum[i] += (p0 + p1) + (p2 + p3);
            pw[i][jp][0] = pkbf(p0, p1);
            pw[i][jp][1] = pkbf(p2, p3);
          }
        }
        bf16x8 pb[2];
        #pragma unroll
        for (int i = 0; i < 2; ++i) {
          u32 fa0 = pw[i][0][0], fb0 = pw[i][1][0];
          u32 fa1 = pw[i][0][1], fb1 = pw[i][1][1];
          plswap(fa0, fb0);
          plswap(fa1, fb1);
          union { u32 u[4]; bf16x8 v; } fu;
          fu.u[0] = fa0; fu.u[1] = fa1; fu.u[2] = fb0; fu.u[3] = fb1;
          pb[i] = fu.v;
        }
        #pragma unroll
        for (int jn = 0; jn < 4; ++jn) {
          bf16x8 vf = *(const bf16x8*)&Vp[(long)(jn*16 + l16)*S_ + kt*128 + ks*32 + quad*8];
          o[0][jn] = __builtin_amdgcn_mfma_f32_16x16x32_bf16(vf, pb[0], o[0][jn], 0, 0, 0);
          o[1][jn] = __builtin_amdgcn_mfma_f32_16x16x32_bf16(vf, pb[1], o[1][jn], 0, 0, 0);
        }
      }
    }

    // -------- epilogue: reduce lsum across quads, scale, store (8B per lane-chunk) ------
    #pragma unroll
    for (int i = 0; i < 2; ++i) {
      lsum[i] += __shfl_xor(lsum[i], 16, 64);
      lsum[i] += __shfl_xor(lsum[i], 32, 64);
      const float inv = 1.0f / lsum[i];
      #pragma unroll
      for (int jn = 0; jn < 4; ++jn) {
        float v0 = o[i][jn][0] * inv, v1 = o[i][jn][1] * inv;
        float v2 = o[i][jn][2] * inv, v3 = o[i][jn][3] * inv;
        uint2 pk;
        pk.x = (u32)f2bf(v0) | ((u32)f2bf(v1) << 16);
        pk.y = (u32)f2bf(v2) | ((u32)f2bf(v3) << 16);
        *(uint2*)&Ob[((long)(b*S_ + q0 + i*16 + l16))*P_ + h*KD_ + jn*16 + quad*4] = pk;
      }
    }
  }
}

extern "C" void kernel_launch(void* const* d_in, const int* in_sizes, int n_in,
                              void* d_out, int out_size, void* d_ws, size_t ws_size,
                              hipStream_t stream) {
  const float* q  = (const float*)d_in[0];
  const float* k  = (const float*)d_in[1];
  const float* v  = (const float*)d_in[2];
  const float* Wq = (const float*)d_in[3];
  const float* bq = (const float*)d_in[4];
  const float* Wk = (const float*)d_in[5];
  const float* bk = (const float*)d_in[6];
  const float* Wv = (const float*)d_in[7];
  const float* bv = (const float*)d_in[8];
  const float* Wo = (const float*)d_in[9];
  const float* bo = (const float*)d_in[10];

  const size_t X_ELEMS = (size_t)M_ * P_;
  const size_t W_ELEMS = (size_t)D_ * P_;
  u16* ws  = (u16*)d_ws;
  u16* Xq  = ws;
  u16* Xk  = Xq  + X_ELEMS;
  u16* Xv  = Xk  + X_ELEMS;
  u16* WqT = Xv  + X_ELEMS;
  u16* WkT = WqT + W_ELEMS;
  u16* WvT = WkT + W_ELEMS;
  u16* WoT = WvT + W_ELEMS;
  u16* Qb  = WoT + W_ELEMS;
  u16* Kb  = Qb  + X_ELEMS;
  u16* Vt  = Kb  + X_ELEMS;      // transposed V: [b][h][d][s]
  u16* Attn = Xq;                // reuse: Xq dead after projections

  cvt3_kernel<<<dim3((unsigned)(X_ELEMS/4/256), 3), 256, 0, stream>>>(q, k, v, Xq, Xk, Xv);

  transpose_cvt4<<<dim3(32, 32, 4), dim3(32, 8), 0, stream>>>(Wq, Wk, Wv, Wo,
                                                              WqT, WkT, WvT, WoT);

  gemm_qkv<<<dim3(M_/128, P_/128, 3), 256, 0, stream>>>(Xq, Xk, Xv, WqT, WkT, WvT,
                                                        bq, bk, bv, Qb, Kb, Vt);

  attn_kernel<<<dim3(512), 256, 0, stream>>>(Qb, Kb, Vt, Attn);

  gemm_out<<<dim3(M_/128, P_/128), 256, 0, stream>>>(Attn, WoT, bo, (float*)d_out);
}

// Round 7
// 340.966 us; speedup vs baseline: 2.1692x; 1.1179x over previous
//
#include <hip/hip_runtime.h>

#define B_ 4
#define S_ 2048
#define D_ 1024
#define H_ 16
#define KD_ 64
#define P_ 1024
#define M_ (B_*S_)

typedef unsigned short u16;
typedef unsigned int u32;
typedef __attribute__((ext_vector_type(2))) unsigned u32x2;
typedef __attribute__((ext_vector_type(4))) float f32x4;
typedef __attribute__((ext_vector_type(8))) __bf16 bf16x8;

__device__ __forceinline__ u16 f2bf(float f) {
  u32 x = __float_as_uint(f);
  return (u16)((x + 0x7fffu + ((x >> 16) & 1u)) >> 16);
}

__device__ __forceinline__ void gl_lds16(const u16* g, u16* l) {
  __builtin_amdgcn_global_load_lds((__attribute__((address_space(1))) void*)g,
                                   (__attribute__((address_space(3))) void*)l, 16, 0, 0);
}

// pack bf16(b)<<16 | bf16(a), round-to-nearest (+0x8000 then take hi16 via v_perm)
__device__ __forceinline__ u32 pkbf(float a, float b) {
  return __builtin_amdgcn_perm(__float_as_uint(b) + 0x8000u,
                               __float_as_uint(a) + 0x8000u, 0x07060302u);
}

// Quad redistribution for P -> PV B-operand (proven in rounds 2-6).
// After this: a = [a@q0, a@q2, b@q0, b@q2], b = [a@q1, a@q3, b@q1, b@q3]
// (x@qN = value of x at source quad N, same l16).
#if __has_builtin(__builtin_amdgcn_permlane32_swap) && __has_builtin(__builtin_amdgcn_permlane16_swap)
__device__ __forceinline__ void plswap(u32& a, u32& b) {
  u32x2 r32 = __builtin_amdgcn_permlane32_swap(a, b, false, false);
  u32x2 r16 = __builtin_amdgcn_permlane16_swap(r32[0], r32[1], false, false);
  a = r16[0]; b = r16[1];
}
#else
__device__ __forceinline__ void plswap(u32& a, u32& b) {
  const int l = threadIdx.x & 63;
  const int quad = l >> 4, l16 = l & 15;
  int i0 = (((quad & 1) * 32) + l16) * 4;
  int i1 = i0 + 64;
  int a_lo = __builtin_amdgcn_ds_bpermute(i0, (int)a);
  int b_lo = __builtin_amdgcn_ds_bpermute(i0, (int)b);
  int a_hi = __builtin_amdgcn_ds_bpermute(i1, (int)a);
  int b_hi = __builtin_amdgcn_ds_bpermute(i1, (int)b);
  u32 na = (quad < 2) ? (u32)a_lo : (u32)b_lo;
  u32 nb = (quad < 2) ? (u32)a_hi : (u32)b_hi;
  a = na; b = nb;
}
#endif

// ---------------- fp32 -> bf16 convert, 3 tensors in one launch ----------------
__global__ void cvt3_kernel(const float* __restrict__ q, const float* __restrict__ k,
                            const float* __restrict__ v,
                            u16* __restrict__ Xq, u16* __restrict__ Xk, u16* __restrict__ Xv) {
  const int z = blockIdx.y;
  const float* in = z == 0 ? q : z == 1 ? k : v;
  u16* out = z == 0 ? Xq : z == 1 ? Xk : Xv;
  int i = blockIdx.x * 256 + threadIdx.x;
  float4 vv = ((const float4*)in)[i];
  ((u32*)out)[i*2+0] = (u32)f2bf(vv.x) | ((u32)f2bf(vv.y) << 16);
  ((u32*)out)[i*2+1] = (u32)f2bf(vv.z) | ((u32)f2bf(vv.w) << 16);
}

// ---------------- transpose 1024x1024 fp32 -> bf16 [C][R], 4 weights ----------------
__global__ void transpose_cvt4(const float* __restrict__ Wq, const float* __restrict__ Wk,
                               const float* __restrict__ Wv, const float* __restrict__ Wo,
                               u16* __restrict__ WqT, u16* __restrict__ WkT,
                               u16* __restrict__ WvT, u16* __restrict__ WoT) {
  const int z = blockIdx.z;
  const float* in = z == 0 ? Wq : z == 1 ? Wk : z == 2 ? Wv : Wo;
  u16* out = z == 0 ? WqT : z == 1 ? WkT : z == 2 ? WvT : WoT;
  __shared__ float tile[32][33];
  int bx = blockIdx.x * 32, by = blockIdx.y * 32;
  int tx = threadIdx.x, ty = threadIdx.y; // block (32,8)
  #pragma unroll
  for (int kk = 0; kk < 4; ++kk)
    tile[ty + kk*8][tx] = in[(by + ty + kk*8) * 1024 + bx + tx];
  __syncthreads();
  #pragma unroll
  for (int kk = 0; kk < 4; ++kk)
    out[(bx + ty + kk*8) * 1024 + by + tx] = f2bf(tile[tx][ty + kk*8]);
}

// ---------------- QKV projection GEMM (batched, z selects), m97 pattern ----------------
// z=0: Q -> Qb [row][P]; z=1: K -> Kb [row][P]; z=2: V -> Vt [b][h][d][s] (transposed!)
__global__ __launch_bounds__(256) void gemm_qkv(
    const u16* __restrict__ Xq, const u16* __restrict__ Xk, const u16* __restrict__ Xv,
    const u16* __restrict__ WqT, const u16* __restrict__ WkT, const u16* __restrict__ WvT,
    const float* __restrict__ bq, const float* __restrict__ bk, const float* __restrict__ bv,
    u16* __restrict__ Qb, u16* __restrict__ Kb, u16* __restrict__ Vt)
{
  constexpr int K = 1024, N = 1024, BK = 32;
  const int z = blockIdx.z;
  const u16* A  = z == 0 ? Xq  : z == 1 ? Xk  : Xv;
  const u16* Bt = z == 0 ? WqT : z == 1 ? WkT : WvT;
  const float* bias = z == 0 ? bq : z == 1 ? bk : bv;

  __shared__ alignas(16) u16 As[128*BK];
  __shared__ alignas(16) u16 Bs[128*BK];
  const int tid = threadIdx.x;
  const int w = tid >> 6, l = tid & 63;
  const int quad = l >> 4, l16 = l & 15;
  const int wm = (w >> 1) * 64, wn = (w & 1) * 64;
  const long mBase = (long)blockIdx.x * 128;
  const int  nBase = blockIdx.y * 128;

  f32x4 acc[4][4] = {};
  const int off0 = w*1024 + l*16;

  for (int kb = 0; kb < K/BK; ++kb) {
    __syncthreads();
    #pragma unroll
    for (int p = 0; p < 2; ++p) {
      int off = p*4096 + off0;
      int row = off >> 6;
      int cb  = off & 63;
      const u16* ga = A  + (mBase + row)*K + kb*BK + (cb >> 1);
      const u16* gb = Bt + ((long)(nBase + row))*K + kb*BK + (cb >> 1);
      gl_lds16(ga, (u16*)((char*)As + p*4096 + w*1024));
      gl_lds16(gb, (u16*)((char*)Bs + p*4096 + w*1024));
    }
    __syncthreads();
    bf16x8 af[4], bf[4];
    #pragma unroll
    for (int i = 0; i < 4; ++i) af[i] = *(const bf16x8*)&As[(wm + i*16 + l16)*BK + quad*8];
    #pragma unroll
    for (int j = 0; j < 4; ++j) bf[j] = *(const bf16x8*)&Bs[(wn + j*16 + l16)*BK + quad*8];
    #pragma unroll
    for (int i = 0; i < 4; ++i)
      #pragma unroll
      for (int j = 0; j < 4; ++j)
        acc[i][j] = __builtin_amdgcn_mfma_f32_16x16x32_bf16(af[i], bf[j], acc[i][j], 0, 0, 0);
  }

  if (z < 2) {
    u16* Cout = z == 0 ? Qb : Kb;
    #pragma unroll
    for (int i = 0; i < 4; ++i)
      #pragma unroll
      for (int j = 0; j < 4; ++j)
        #pragma unroll
        for (int r = 0; r < 4; ++r) {
          long row = mBase + wm + i*16 + quad*4 + r;
          int  col = nBase + wn + j*16 + l16;
          Cout[row*N + col] = f2bf(acc[i][j][r] + bias[col]);
        }
  } else {
    // V: write transposed per head: Vt[(b*1024 + h*64 + d)*2048 + s]; 4 consecutive s -> 8B stores
    #pragma unroll
    for (int i = 0; i < 4; ++i)
      #pragma unroll
      for (int j = 0; j < 4; ++j) {
        int  col  = nBase + wn + j*16 + l16;       // = h*64+d
        long row0 = mBase + wm + i*16 + quad*4;    // token; +r consecutive
        int  bb = (int)(row0 >> 11);
        int  ss = (int)(row0 & 2047);
        float bcol = bias[col];
        float v0 = acc[i][j][0] + bcol, v1 = acc[i][j][1] + bcol;
        float v2 = acc[i][j][2] + bcol, v3 = acc[i][j][3] + bcol;
        uint2 pk;
        pk.x = (u32)f2bf(v0) | ((u32)f2bf(v1) << 16);
        pk.y = (u32)f2bf(v2) | ((u32)f2bf(v3) << 16);
        *(uint2*)&Vt[((long)(bb*16) * 64 + col) * 2048 + ss] = pk;
      }
  }
}

// ---------------- output projection GEMM (fp32 out) ----------------
__global__ __launch_bounds__(256) void gemm_out(const u16* __restrict__ A,
                                                const u16* __restrict__ Bt,
                                                const float* __restrict__ bias,
                                                float* __restrict__ Cout)
{
  constexpr int K = 1024, N = 1024, BK = 32;
  __shared__ alignas(16) u16 As[128*BK];
  __shared__ alignas(16) u16 Bs[128*BK];
  const int tid = threadIdx.x;
  const int w = tid >> 6, l = tid & 63;
  const int quad = l >> 4, l16 = l & 15;
  const int wm = (w >> 1) * 64, wn = (w & 1) * 64;
  const long mBase = (long)blockIdx.x * 128;
  const int  nBase = blockIdx.y * 128;

  f32x4 acc[4][4] = {};
  const int off0 = w*1024 + l*16;

  for (int kb = 0; kb < K/BK; ++kb) {
    __syncthreads();
    #pragma unroll
    for (int p = 0; p < 2; ++p) {
      int off = p*4096 + off0;
      int row = off >> 6;
      int cb  = off & 63;
      const u16* ga = A  + (mBase + row)*K + kb*BK + (cb >> 1);
      const u16* gb = Bt + ((long)(nBase + row))*K + kb*BK + (cb >> 1);
      gl_lds16(ga, (u16*)((char*)As + p*4096 + w*1024));
      gl_lds16(gb, (u16*)((char*)Bs + p*4096 + w*1024));
    }
    __syncthreads();
    bf16x8 af[4], bf[4];
    #pragma unroll
    for (int i = 0; i < 4; ++i) af[i] = *(const bf16x8*)&As[(wm + i*16 + l16)*BK + quad*8];
    #pragma unroll
    for (int j = 0; j < 4; ++j) bf[j] = *(const bf16x8*)&Bs[(wn + j*16 + l16)*BK + quad*8];
    #pragma unroll
    for (int i = 0; i < 4; ++i)
      #pragma unroll
      for (int j = 0; j < 4; ++j)
        acc[i][j] = __builtin_amdgcn_mfma_f32_16x16x32_bf16(af[i], bf[j], acc[i][j], 0, 0, 0);
  }

  #pragma unroll
  for (int i = 0; i < 4; ++i)
    #pragma unroll
    for (int j = 0; j < 4; ++j)
      #pragma unroll
      for (int r = 0; r < 4; ++r) {
        long row = mBase + wm + i*16 + quad*4 + r;
        int  col = nBase + wn + j*16 + l16;
        Cout[row*N + col] = acc[i][j][r] + bias[col];
      }
}

// ---------------- flash attention: 64 q-rows/wave, shared K/V, K reg-dbuf ----------------
// grid 1024 = qtr(16, qt=15 first) x [b(4) x h(16)]; 128 threads = 2 waves.
// Wave w (=tid>>6) owns q rows [qt*128 + w*64, +64): FOUR 16-row sub-tiles i=0..3.
// K and V fragments are shared by all 4 sub-tiles (only qf/pb differ per i) ->
// per iteration: 8 loads feed 32 MFMA (2x round 6's intensity), and 4 independent
// QK chains give the scheduler ILP. V loads issue at compute start; PV uses them
// after ~16 MFMA + 32 exp of QK work -> latency hidden without dbuf. K keeps the
// depth-1 named double-buffer (proven round 6). launch_bounds(128,2): 256-VGPR
// ceiling, state ~220 regs -> no spill (round-4 tripwire: watch WRITE_SIZE).
// S^T = K*Q^T; PV B-operand via plswap quad permutation. Static-shift softmax:
// exponent = c1*s - sl2*k, bounded; masked diag via exp(-1e30)=0 (exact).
__global__ __launch_bounds__(128, 2) void attn_kernel(const u16* __restrict__ Qb,
                                                      const u16* __restrict__ Kb,
                                                      const u16* __restrict__ Vt,
                                                      u16* __restrict__ Ob)
{
  const int n = blockIdx.x;
  const int qt = 15 - (n >> 6);
  const int r6 = n & 63;
  const int b = r6 >> 4, h = r6 & 15;
  const int w = threadIdx.x >> 6;        // 0/1: which 64-row half of the 128-q tile
  const int l = threadIdx.x & 63;
  const int quad = l >> 4, l16 = l & 15;
  const float LOG2E = 1.44269504089f;
  const float slope = exp2f(-0.5f * (float)(h + 1));
  const float c1  = 0.125f * LOG2E;
  const float sl2 = slope * LOG2E;
  const float rs1 = sl2, rs2 = 2.f*sl2, rs3 = 3.f*sl2;

  const int q0 = qt*128 + w*64;
  const u16* Qp = Qb + ((long)(b*S_ + q0))*P_ + h*KD_;
  const u16* Kp = Kb + ((long)(b*S_))*P_ + h*KD_;
  const u16* Vp = Vt + ((long)(b*H_ + h))*KD_*S_;

  // Q fragments (MFMA B-operand for S^T = K*Q^T), 4 sub-tiles x 2 k-halves
  bf16x8 qf[4][2];
  #pragma unroll
  for (int i = 0; i < 4; ++i)
    #pragma unroll
    for (int kk = 0; kk < 2; ++kk)
      qf[i][kk] = *(const bf16x8*)&Qp[(long)(i*16 + l16)*P_ + kk*32 + quad*8];

  f32x4 o[4][4] = {};           // [i][jn]: O^T rows d (jn*16+quad*4+r), cols q=l16
  float lsum[4] = {0.f, 0.f, 0.f, 0.f};

  // -------- pipelined full (non-diagonal) key tiles: it = kt*4 + ks --------
  auto kissue = [&](int it, bf16x8& k00, bf16x8& k01, bf16x8& k10, bf16x8& k11) {
    const int kt = it >> 2, ks = it & 3;
    const u16* kp = Kp + (long)(kt*128 + l16 + 2*ks*16)*P_;
    k00 = *(const bf16x8*)(kp + quad*8);
    k01 = *(const bf16x8*)(kp + 32 + quad*8);
    k10 = *(const bf16x8*)(kp + 16*P_ + quad*8);
    k11 = *(const bf16x8*)(kp + 16*P_ + 32 + quad*8);
  };
  auto compute = [&](int it, const bf16x8& k00, const bf16x8& k01,
                     const bf16x8& k10, const bf16x8& k11) {
    const int kt = it >> 2, ks = it & 3;
    // V loads first: used only after the QK+exp block -> latency hidden
    const u16* vp = Vp + (long)l16*S_ + kt*128 + ks*32 + quad*8;
    bf16x8 v0 = *(const bf16x8*)(vp);
    bf16x8 v1 = *(const bf16x8*)(vp + 16*S_);
    bf16x8 v2 = *(const bf16x8*)(vp + 32*S_);
    bf16x8 v3 = *(const bf16x8*)(vp + 48*S_);
    const float kb0 = (float)(kt*128 + 2*ks*16 + quad*4);
    u32 pw0[4][2], pw1[4][2];
    {
      const float bij = -sl2 * kb0;
      #pragma unroll
      for (int i = 0; i < 4; ++i) {
        f32x4 t = {};
        t = __builtin_amdgcn_mfma_f32_16x16x32_bf16(k00, qf[i][0], t, 0, 0, 0);
        t = __builtin_amdgcn_mfma_f32_16x16x32_bf16(k01, qf[i][1], t, 0, 0, 0);
        float p0 = __builtin_amdgcn_exp2f(fmaf(t[0], c1, bij));
        float p1 = __builtin_amdgcn_exp2f(fmaf(t[1], c1, bij) - rs1);
        float p2 = __builtin_amdgcn_exp2f(fmaf(t[2], c1, bij) - rs2);
        float p3 = __builtin_amdgcn_exp2f(fmaf(t[3], c1, bij) - rs3);
        lsum[i] += (p0 + p1) + (p2 + p3);
        pw0[i][0] = pkbf(p0, p1);
        pw0[i][1] = pkbf(p2, p3);
      }
    }
    {
      const float bij = -sl2 * (kb0 + 16.f);
      #pragma unroll
      for (int i = 0; i < 4; ++i) {
        f32x4 t = {};
        t = __builtin_amdgcn_mfma_f32_16x16x32_bf16(k10, qf[i][0], t, 0, 0, 0);
        t = __builtin_amdgcn_mfma_f32_16x16x32_bf16(k11, qf[i][1], t, 0, 0, 0);
        float p0 = __builtin_amdgcn_exp2f(fmaf(t[0], c1, bij));
        float p1 = __builtin_amdgcn_exp2f(fmaf(t[1], c1, bij) - rs1);
        float p2 = __builtin_amdgcn_exp2f(fmaf(t[2], c1, bij) - rs2);
        float p3 = __builtin_amdgcn_exp2f(fmaf(t[3], c1, bij) - rs3);
        lsum[i] += (p0 + p1) + (p2 + p3);
        pw1[i][0] = pkbf(p0, p1);
        pw1[i][1] = pkbf(p2, p3);
      }
    }
    #pragma unroll
    for (int i = 0; i < 4; ++i) {
      u32 fa0 = pw0[i][0], fb0 = pw1[i][0];
      u32 fa1 = pw0[i][1], fb1 = pw1[i][1];
      plswap(fa0, fb0);
      plswap(fa1, fb1);
      union { u32 u[4]; bf16x8 v; } fu;
      fu.u[0] = fa0; fu.u[1] = fa1; fu.u[2] = fb0; fu.u[3] = fb1;
      const bf16x8 pb = fu.v;
      o[i][0] = __builtin_amdgcn_mfma_f32_16x16x32_bf16(v0, pb, o[i][0], 0, 0, 0);
      o[i][1] = __builtin_amdgcn_mfma_f32_16x16x32_bf16(v1, pb, o[i][1], 0, 0, 0);
      o[i][2] = __builtin_amdgcn_mfma_f32_16x16x32_bf16(v2, pb, o[i][2], 0, 0, 0);
      o[i][3] = __builtin_amdgcn_mfma_f32_16x16x32_bf16(v3, pb, o[i][3], 0, 0, 0);
    }
  };

  const int nit = qt * 4;
  if (nit > 0) {
    bf16x8 ak00, ak01, ak10, ak11;   // K buffer A
    bf16x8 bk00, bk01, bk10, bk11;   // K buffer B
    kissue(0, ak00, ak01, ak10, ak11);
    int it = 0;
    while (true) {
      if (it + 1 < nit) kissue(it + 1, bk00, bk01, bk10, bk11);
      compute(it, ak00, ak01, ak10, ak11);
      ++it; if (it == nit) break;
      if (it + 1 < nit) kissue(it + 1, ak00, ak01, ak10, ak11);
      compute(it, bk00, bk01, bk10, bk11);
      ++it; if (it == nit) break;
    }
  }

  // -------- diagonal tile (kt == qt): masked, ks up to wave's row range --------
  {
    const int kt = qt;
    const int ksmax = 2*w + 2;  // w=0: keys 0..63 (ks 0..1); w=1: keys 0..127 (ks 0..3)
    const u16* kts = Kp + (long)(kt*128 + l16)*P_;
    for (int ks = 0; ks < ksmax; ++ks) {
      const u16* vp = Vp + (long)l16*S_ + kt*128 + ks*32 + quad*8;
      bf16x8 v0 = *(const bf16x8*)(vp);
      bf16x8 v1 = *(const bf16x8*)(vp + 16*S_);
      bf16x8 v2 = *(const bf16x8*)(vp + 32*S_);
      bf16x8 v3 = *(const bf16x8*)(vp + 48*S_);
      u32 pw[4][2][2];          // [i][jp][c]
      #pragma unroll
      for (int jp = 0; jp < 2; ++jp) {
        const int j = 2*ks + jp;
        const u16* kp = kts + (long)(j*16)*P_;
        bf16x8 kf0 = *(const bf16x8*)(kp + quad*8);
        bf16x8 kf1 = *(const bf16x8*)(kp + 32 + quad*8);
        const int kl0 = j*16 + quad*4;  // tile-local key of r=0
        const float bij = -sl2 * (float)(kt*128 + kl0);
        #pragma unroll
        for (int i = 0; i < 4; ++i) {
          const int ql = w*64 + i*16 + l16;   // tile-local q row
          f32x4 t = {};
          t = __builtin_amdgcn_mfma_f32_16x16x32_bf16(kf0, qf[i][0], t, 0, 0, 0);
          t = __builtin_amdgcn_mfma_f32_16x16x32_bf16(kf1, qf[i][1], t, 0, 0, 0);
          float x0 = fmaf(t[0], c1, bij);
          float x1 = fmaf(t[1], c1, bij) - rs1;
          float x2 = fmaf(t[2], c1, bij) - rs2;
          float x3 = fmaf(t[3], c1, bij) - rs3;
          if (kl0 + 0 > ql) x0 = -1e30f;
          if (kl0 + 1 > ql) x1 = -1e30f;
          if (kl0 + 2 > ql) x2 = -1e30f;
          if (kl0 + 3 > ql) x3 = -1e30f;
          float p0 = __builtin_amdgcn_exp2f(x0);
          float p1 = __builtin_amdgcn_exp2f(x1);
          float p2 = __builtin_amdgcn_exp2f(x2);
          float p3 = __builtin_amdgcn_exp2f(x3);
          lsum[i] += (p0 + p1) + (p2 + p3);
          pw[i][jp][0] = pkbf(p0, p1);
          pw[i][jp][1] = pkbf(p2, p3);
        }
      }
      #pragma unroll
      for (int i = 0; i < 4; ++i) {
        u32 fa0 = pw[i][0][0], fb0 = pw[i][1][0];
        u32 fa1 = pw[i][0][1], fb1 = pw[i][1][1];
        plswap(fa0, fb0);
        plswap(fa1, fb1);
        union { u32 u[4]; bf16x8 v; } fu;
        fu.u[0] = fa0; fu.u[1] = fa1; fu.u[2] = fb0; fu.u[3] = fb1;
        const bf16x8 pb = fu.v;
        o[i][0] = __builtin_amdgcn_mfma_f32_16x16x32_bf16(v0, pb, o[i][0], 0, 0, 0);
        o[i][1] = __builtin_amdgcn_mfma_f32_16x16x32_bf16(v1, pb, o[i][1], 0, 0, 0);
        o[i][2] = __builtin_amdgcn_mfma_f32_16x16x32_bf16(v2, pb, o[i][2], 0, 0, 0);
        o[i][3] = __builtin_amdgcn_mfma_f32_16x16x32_bf16(v3, pb, o[i][3], 0, 0, 0);
      }
    }
  }

  // -------- epilogue: reduce lsum across quads, scale, store (8B per lane-chunk) --------
  #pragma unroll
  for (int i = 0; i < 4; ++i) {
    lsum[i] += __shfl_xor(lsum[i], 16, 64);
    lsum[i] += __shfl_xor(lsum[i], 32, 64);
    const float inv = 1.0f / lsum[i];
    #pragma unroll
    for (int jn = 0; jn < 4; ++jn) {
      float v0 = o[i][jn][0] * inv, v1 = o[i][jn][1] * inv;
      float v2 = o[i][jn][2] * inv, v3 = o[i][jn][3] * inv;
      uint2 pk;
      pk.x = (u32)f2bf(v0) | ((u32)f2bf(v1) << 16);
      pk.y = (u32)f2bf(v2) | ((u32)f2bf(v3) << 16);
      *(uint2*)&Ob[((long)(b*S_ + q0 + i*16 + l16))*P_ + h*KD_ + jn*16 + quad*4] = pk;
    }
  }
}

extern "C" void kernel_launch(void* const* d_in, const int* in_sizes, int n_in,
                              void* d_out, int out_size, void* d_ws, size_t ws_size,
                              hipStream_t stream) {
  const float* q  = (const float*)d_in[0];
  const float* k  = (const float*)d_in[1];
  const float* v  = (const float*)d_in[2];
  const float* Wq = (const float*)d_in[3];
  const float* bq = (const float*)d_in[4];
  const float* Wk = (const float*)d_in[5];
  const float* bk = (const float*)d_in[6];
  const float* Wv = (const float*)d_in[7];
  const float* bv = (const float*)d_in[8];
  const float* Wo = (const float*)d_in[9];
  const float* bo = (const float*)d_in[10];

  const size_t X_ELEMS = (size_t)M_ * P_;
  const size_t W_ELEMS = (size_t)D_ * P_;
  u16* ws  = (u16*)d_ws;
  u16* Xq  = ws;
  u16* Xk  = Xq  + X_ELEMS;
  u16* Xv  = Xk  + X_ELEMS;
  u16* WqT = Xv  + X_ELEMS;
  u16* WkT = WqT + W_ELEMS;
  u16* WvT = WkT + W_ELEMS;
  u16* WoT = WvT + W_ELEMS;
  u16* Qb  = WoT + W_ELEMS;
  u16* Kb  = Qb  + X_ELEMS;
  u16* Vt  = Kb  + X_ELEMS;      // transposed V: [b][h][d][s]
  u16* Attn = Xq;                // reuse: Xq dead after projections

  cvt3_kernel<<<dim3((unsigned)(X_ELEMS/4/256), 3), 256, 0, stream>>>(q, k, v, Xq, Xk, Xv);

  transpose_cvt4<<<dim3(32, 32, 4), dim3(32, 8), 0, stream>>>(Wq, Wk, Wv, Wo,
                                                              WqT, WkT, WvT, WoT);

  gemm_qkv<<<dim3(M_/128, P_/128, 3), 256, 0, stream>>>(Xq, Xk, Xv, WqT, WkT, WvT,
                                                        bq, bk, bv, Qb, Kb, Vt);

  attn_kernel<<<dim3(1024), 128, 0, stream>>>(Qb, Kb, Vt, Attn);

  gemm_out<<<dim3(M_/128, P_/128), 256, 0, stream>>>(Attn, WoT, bo, (float*)d_out);
}

// Round 8
// 333.869 us; speedup vs baseline: 2.2153x; 1.0213x over previous
//
#include <hip/hip_runtime.h>

#define B_ 4
#define S_ 2048
#define D_ 1024
#define H_ 16
#define KD_ 64
#define P_ 1024
#define M_ (B_*S_)

typedef unsigned short u16;
typedef unsigned int u32;
typedef __attribute__((ext_vector_type(2))) unsigned u32x2;
typedef __attribute__((ext_vector_type(4))) float f32x4;
typedef __attribute__((ext_vector_type(8))) __bf16 bf16x8;

__device__ __forceinline__ u16 f2bf(float f) {
  u32 x = __float_as_uint(f);
  return (u16)((x + 0x7fffu + ((x >> 16) & 1u)) >> 16);
}

__device__ __forceinline__ void gl_lds16(const u16* g, u16* l) {
  __builtin_amdgcn_global_load_lds((__attribute__((address_space(1))) void*)g,
                                   (__attribute__((address_space(3))) void*)l, 16, 0, 0);
}

// pack bf16(b)<<16 | bf16(a), round-to-nearest (+0x8000 then take hi16 via v_perm)
__device__ __forceinline__ u32 pkbf(float a, float b) {
  return __builtin_amdgcn_perm(__float_as_uint(b) + 0x8000u,
                               __float_as_uint(a) + 0x8000u, 0x07060302u);
}

// Quad redistribution for P -> PV B-operand (proven in rounds 2-7).
// After this: a = [a@q0, a@q2, b@q0, b@q2], b = [a@q1, a@q3, b@q1, b@q3]
// (x@qN = value of x at source quad N, same l16).
#if __has_builtin(__builtin_amdgcn_permlane32_swap) && __has_builtin(__builtin_amdgcn_permlane16_swap)
__device__ __forceinline__ void plswap(u32& a, u32& b) {
  u32x2 r32 = __builtin_amdgcn_permlane32_swap(a, b, false, false);
  u32x2 r16 = __builtin_amdgcn_permlane16_swap(r32[0], r32[1], false, false);
  a = r16[0]; b = r16[1];
}
#else
__device__ __forceinline__ void plswap(u32& a, u32& b) {
  const int l = threadIdx.x & 63;
  const int quad = l >> 4, l16 = l & 15;
  int i0 = (((quad & 1) * 32) + l16) * 4;
  int i1 = i0 + 64;
  int a_lo = __builtin_amdgcn_ds_bpermute(i0, (int)a);
  int b_lo = __builtin_amdgcn_ds_bpermute(i0, (int)b);
  int a_hi = __builtin_amdgcn_ds_bpermute(i1, (int)a);
  int b_hi = __builtin_amdgcn_ds_bpermute(i1, (int)b);
  u32 na = (quad < 2) ? (u32)a_lo : (u32)b_lo;
  u32 nb = (quad < 2) ? (u32)a_hi : (u32)b_hi;
  a = na; b = nb;
}
#endif

// ---------------- fp32 -> bf16 convert, 3 tensors in one launch ----------------
__global__ void cvt3_kernel(const float* __restrict__ q, const float* __restrict__ k,
                            const float* __restrict__ v,
                            u16* __restrict__ Xq, u16* __restrict__ Xk, u16* __restrict__ Xv) {
  const int z = blockIdx.y;
  const float* in = z == 0 ? q : z == 1 ? k : v;
  u16* out = z == 0 ? Xq : z == 1 ? Xk : Xv;
  int i = blockIdx.x * 256 + threadIdx.x;
  float4 vv = ((const float4*)in)[i];
  ((u32*)out)[i*2+0] = (u32)f2bf(vv.x) | ((u32)f2bf(vv.y) << 16);
  ((u32*)out)[i*2+1] = (u32)f2bf(vv.z) | ((u32)f2bf(vv.w) << 16);
}

// ---------------- transpose 1024x1024 fp32 -> bf16 [C][R], 4 weights ----------------
__global__ void transpose_cvt4(const float* __restrict__ Wq, const float* __restrict__ Wk,
                               const float* __restrict__ Wv, const float* __restrict__ Wo,
                               u16* __restrict__ WqT, u16* __restrict__ WkT,
                               u16* __restrict__ WvT, u16* __restrict__ WoT) {
  const int z = blockIdx.z;
  const float* in = z == 0 ? Wq : z == 1 ? Wk : z == 2 ? Wv : Wo;
  u16* out = z == 0 ? WqT : z == 1 ? WkT : z == 2 ? WvT : WoT;
  __shared__ float tile[32][33];
  int bx = blockIdx.x * 32, by = blockIdx.y * 32;
  int tx = threadIdx.x, ty = threadIdx.y; // block (32,8)
  #pragma unroll
  for (int kk = 0; kk < 4; ++kk)
    tile[ty + kk*8][tx] = in[(by + ty + kk*8) * 1024 + bx + tx];
  __syncthreads();
  #pragma unroll
  for (int kk = 0; kk < 4; ++kk)
    out[(bx + ty + kk*8) * 1024 + by + tx] = f2bf(tile[tx][ty + kk*8]);
}

// ---------------- QKV projection GEMM (batched, z selects), m97 pattern ----------------
// z=0: Q -> Qb [row][P]; z=1: K -> Kb [row][P]; z=2: V -> Vt [b][h][d][s] (transposed!)
__global__ __launch_bounds__(256) void gemm_qkv(
    const u16* __restrict__ Xq, const u16* __restrict__ Xk, const u16* __restrict__ Xv,
    const u16* __restrict__ WqT, const u16* __restrict__ WkT, const u16* __restrict__ WvT,
    const float* __restrict__ bq, const float* __restrict__ bk, const float* __restrict__ bv,
    u16* __restrict__ Qb, u16* __restrict__ Kb, u16* __restrict__ Vt)
{
  constexpr int K = 1024, N = 1024, BK = 32;
  const int z = blockIdx.z;
  const u16* A  = z == 0 ? Xq  : z == 1 ? Xk  : Xv;
  const u16* Bt = z == 0 ? WqT : z == 1 ? WkT : WvT;
  const float* bias = z == 0 ? bq : z == 1 ? bk : bv;

  __shared__ alignas(16) u16 As[128*BK];
  __shared__ alignas(16) u16 Bs[128*BK];
  const int tid = threadIdx.x;
  const int w = tid >> 6, l = tid & 63;
  const int quad = l >> 4, l16 = l & 15;
  const int wm = (w >> 1) * 64, wn = (w & 1) * 64;
  const long mBase = (long)blockIdx.x * 128;
  const int  nBase = blockIdx.y * 128;

  f32x4 acc[4][4] = {};
  const int off0 = w*1024 + l*16;

  for (int kb = 0; kb < K/BK; ++kb) {
    __syncthreads();
    #pragma unroll
    for (int p = 0; p < 2; ++p) {
      int off = p*4096 + off0;
      int row = off >> 6;
      int cb  = off & 63;
      const u16* ga = A  + (mBase + row)*K + kb*BK + (cb >> 1);
      const u16* gb = Bt + ((long)(nBase + row))*K + kb*BK + (cb >> 1);
      gl_lds16(ga, (u16*)((char*)As + p*4096 + w*1024));
      gl_lds16(gb, (u16*)((char*)Bs + p*4096 + w*1024));
    }
    __syncthreads();
    bf16x8 af[4], bf[4];
    #pragma unroll
    for (int i = 0; i < 4; ++i) af[i] = *(const bf16x8*)&As[(wm + i*16 + l16)*BK + quad*8];
    #pragma unroll
    for (int j = 0; j < 4; ++j) bf[j] = *(const bf16x8*)&Bs[(wn + j*16 + l16)*BK + quad*8];
    #pragma unroll
    for (int i = 0; i < 4; ++i)
      #pragma unroll
      for (int j = 0; j < 4; ++j)
        acc[i][j] = __builtin_amdgcn_mfma_f32_16x16x32_bf16(af[i], bf[j], acc[i][j], 0, 0, 0);
  }

  if (z < 2) {
    u16* Cout = z == 0 ? Qb : Kb;
    #pragma unroll
    for (int i = 0; i < 4; ++i)
      #pragma unroll
      for (int j = 0; j < 4; ++j)
        #pragma unroll
        for (int r = 0; r < 4; ++r) {
          long row = mBase + wm + i*16 + quad*4 + r;
          int  col = nBase + wn + j*16 + l16;
          Cout[row*N + col] = f2bf(acc[i][j][r] + bias[col]);
        }
  } else {
    // V: write transposed per head: Vt[(b*1024 + h*64 + d)*2048 + s]; 4 consecutive s -> 8B stores
    #pragma unroll
    for (int i = 0; i < 4; ++i)
      #pragma unroll
      for (int j = 0; j < 4; ++j) {
        int  col  = nBase + wn + j*16 + l16;       // = h*64+d
        long row0 = mBase + wm + i*16 + quad*4;    // token; +r consecutive
        int  bb = (int)(row0 >> 11);
        int  ss = (int)(row0 & 2047);
        float bcol = bias[col];
        float v0 = acc[i][j][0] + bcol, v1 = acc[i][j][1] + bcol;
        float v2 = acc[i][j][2] + bcol, v3 = acc[i][j][3] + bcol;
        uint2 pk;
        pk.x = (u32)f2bf(v0) | ((u32)f2bf(v1) << 16);
        pk.y = (u32)f2bf(v2) | ((u32)f2bf(v3) << 16);
        *(uint2*)&Vt[((long)(bb*16) * 64 + col) * 2048 + ss] = pk;
      }
  }
}

// ---------------- output projection GEMM (fp32 out) ----------------
__global__ __launch_bounds__(256) void gemm_out(const u16* __restrict__ A,
                                                const u16* __restrict__ Bt,
                                                const float* __restrict__ bias,
                                                float* __restrict__ Cout)
{
  constexpr int K = 1024, N = 1024, BK = 32;
  __shared__ alignas(16) u16 As[128*BK];
  __shared__ alignas(16) u16 Bs[128*BK];
  const int tid = threadIdx.x;
  const int w = tid >> 6, l = tid & 63;
  const int quad = l >> 4, l16 = l & 15;
  const int wm = (w >> 1) * 64, wn = (w & 1) * 64;
  const long mBase = (long)blockIdx.x * 128;
  const int  nBase = blockIdx.y * 128;

  f32x4 acc[4][4] = {};
  const int off0 = w*1024 + l*16;

  for (int kb = 0; kb < K/BK; ++kb) {
    __syncthreads();
    #pragma unroll
    for (int p = 0; p < 2; ++p) {
      int off = p*4096 + off0;
      int row = off >> 6;
      int cb  = off & 63;
      const u16* ga = A  + (mBase + row)*K + kb*BK + (cb >> 1);
      const u16* gb = Bt + ((long)(nBase + row))*K + kb*BK + (cb >> 1);
      gl_lds16(ga, (u16*)((char*)As + p*4096 + w*1024));
      gl_lds16(gb, (u16*)((char*)Bs + p*4096 + w*1024));
    }
    __syncthreads();
    bf16x8 af[4], bf[4];
    #pragma unroll
    for (int i = 0; i < 4; ++i) af[i] = *(const bf16x8*)&As[(wm + i*16 + l16)*BK + quad*8];
    #pragma unroll
    for (int j = 0; j < 4; ++j) bf[j] = *(const bf16x8*)&Bs[(wn + j*16 + l16)*BK + quad*8];
    #pragma unroll
    for (int i = 0; i < 4; ++i)
      #pragma unroll
      for (int j = 0; j < 4; ++j)
        acc[i][j] = __builtin_amdgcn_mfma_f32_16x16x32_bf16(af[i], bf[j], acc[i][j], 0, 0, 0);
  }

  #pragma unroll
  for (int i = 0; i < 4; ++i)
    #pragma unroll
    for (int j = 0; j < 4; ++j)
      #pragma unroll
      for (int r = 0; r < 4; ++r) {
        long row = mBase + wm + i*16 + quad*4 + r;
        int  col = nBase + wn + j*16 + l16;
        Cout[row*N + col] = acc[i][j][r] + bias[col];
      }
}

// ---------------- flash attention: split-K wave pairs, 64 q-rows/wave ----------------
// grid 1024 = qtr(16, qt=15 first) x [b(4) x h(16)]; 256 threads = 4 waves.
// Wave (wq, wk): wq = q-half (rows qt*128 + wq*64, 64 rows = 4 sub-tiles), wk = kt-half.
// wk=0 handles kt in [0, ceil(qt/2)); wk=1 handles the rest + masked diagonal, then the
// pair combines partial O/lsum through LDS (one barrier) and wk=1 stores. Total K/V
// traffic unchanged vs round 7 (each (q-tile, kt) once); wave count 2048 -> 4096
// (16/CU available vs 8) attacking the measured ~50% per-wave stall at 1 wave/SIMD.
// Per-wave inner loop identical to round 7: K reg-dbuf depth 1, V loads at compute
// start, 8 loads -> 32 MFMA, plswap P redistribution, static-shift softmax.
// launch_bounds(256,2): 256-VGPR ceiling, no spill possible (round-4 tripwire:
// WRITE_SIZE must stay ~16 MB). LDS 34 KB/block -> 4 blocks/CU fits 136/160 KB.
__global__ __launch_bounds__(256, 2) void attn_kernel(const u16* __restrict__ Qb,
                                                      const u16* __restrict__ Kb,
                                                      const u16* __restrict__ Vt,
                                                      u16* __restrict__ Ob)
{
  const int n = blockIdx.x;
  const int qt = 15 - (n >> 6);
  const int r6 = n & 63;
  const int b = r6 >> 4, h = r6 & 15;
  const int wq = threadIdx.x >> 7;        // 0/1: q-half of the 128-q tile
  const int wk = (threadIdx.x >> 6) & 1;  // 0/1: kt-half
  const int l = threadIdx.x & 63;
  const int quad = l >> 4, l16 = l & 15;
  const float LOG2E = 1.44269504089f;
  const float slope = exp2f(-0.5f * (float)(h + 1));
  const float c1  = 0.125f * LOG2E;
  const float sl2 = slope * LOG2E;
  const float rs1 = sl2, rs2 = 2.f*sl2, rs3 = 3.f*sl2;

  const int q0 = qt*128 + wq*64;
  const u16* Qp = Qb + ((long)(b*S_ + q0))*P_ + h*KD_;
  const u16* Kp = Kb + ((long)(b*S_))*P_ + h*KD_;
  const u16* Vp = Vt + ((long)(b*H_ + h))*KD_*S_;

  // Q fragments (MFMA B-operand for S^T = K*Q^T), 4 sub-tiles x 2 k-halves
  bf16x8 qf[4][2];
  #pragma unroll
  for (int i = 0; i < 4; ++i)
    #pragma unroll
    for (int kk = 0; kk < 2; ++kk)
      qf[i][kk] = *(const bf16x8*)&Qp[(long)(i*16 + l16)*P_ + kk*32 + quad*8];

  f32x4 o[4][4] = {};           // [i][jn]: O^T rows d (jn*16+quad*4+r), cols q=l16
  float lsum[4] = {0.f, 0.f, 0.f, 0.f};

  // -------- pipelined full (non-diagonal) key tiles: it = kt*4 + ks --------
  auto kissue = [&](int it, bf16x8& k00, bf16x8& k01, bf16x8& k10, bf16x8& k11) {
    const int kt = it >> 2, ks = it & 3;
    const u16* kp = Kp + (long)(kt*128 + l16 + 2*ks*16)*P_;
    k00 = *(const bf16x8*)(kp + quad*8);
    k01 = *(const bf16x8*)(kp + 32 + quad*8);
    k10 = *(const bf16x8*)(kp + 16*P_ + quad*8);
    k11 = *(const bf16x8*)(kp + 16*P_ + 32 + quad*8);
  };
  auto compute = [&](int it, const bf16x8& k00, const bf16x8& k01,
                     const bf16x8& k10, const bf16x8& k11) {
    const int kt = it >> 2, ks = it & 3;
    // V loads first: used only after the QK+exp block -> latency hidden
    const u16* vp = Vp + (long)l16*S_ + kt*128 + ks*32 + quad*8;
    bf16x8 v0 = *(const bf16x8*)(vp);
    bf16x8 v1 = *(const bf16x8*)(vp + 16*S_);
    bf16x8 v2 = *(const bf16x8*)(vp + 32*S_);
    bf16x8 v3 = *(const bf16x8*)(vp + 48*S_);
    const float kb0 = (float)(kt*128 + 2*ks*16 + quad*4);
    u32 pw0[4][2], pw1[4][2];
    {
      const float bij = -sl2 * kb0;
      #pragma unroll
      for (int i = 0; i < 4; ++i) {
        f32x4 t = {};
        t = __builtin_amdgcn_mfma_f32_16x16x32_bf16(k00, qf[i][0], t, 0, 0, 0);
        t = __builtin_amdgcn_mfma_f32_16x16x32_bf16(k01, qf[i][1], t, 0, 0, 0);
        float p0 = __builtin_amdgcn_exp2f(fmaf(t[0], c1, bij));
        float p1 = __builtin_amdgcn_exp2f(fmaf(t[1], c1, bij) - rs1);
        float p2 = __builtin_amdgcn_exp2f(fmaf(t[2], c1, bij) - rs2);
        float p3 = __builtin_amdgcn_exp2f(fmaf(t[3], c1, bij) - rs3);
        lsum[i] += (p0 + p1) + (p2 + p3);
        pw0[i][0] = pkbf(p0, p1);
        pw0[i][1] = pkbf(p2, p3);
      }
    }
    {
      const float bij = -sl2 * (kb0 + 16.f);
      #pragma unroll
      for (int i = 0; i < 4; ++i) {
        f32x4 t = {};
        t = __builtin_amdgcn_mfma_f32_16x16x32_bf16(k10, qf[i][0], t, 0, 0, 0);
        t = __builtin_amdgcn_mfma_f32_16x16x32_bf16(k11, qf[i][1], t, 0, 0, 0);
        float p0 = __builtin_amdgcn_exp2f(fmaf(t[0], c1, bij));
        float p1 = __builtin_amdgcn_exp2f(fmaf(t[1], c1, bij) - rs1);
        float p2 = __builtin_amdgcn_exp2f(fmaf(t[2], c1, bij) - rs2);
        float p3 = __builtin_amdgcn_exp2f(fmaf(t[3], c1, bij) - rs3);
        lsum[i] += (p0 + p1) + (p2 + p3);
        pw1[i][0] = pkbf(p0, p1);
        pw1[i][1] = pkbf(p2, p3);
      }
    }
    #pragma unroll
    for (int i = 0; i < 4; ++i) {
      u32 fa0 = pw0[i][0], fb0 = pw1[i][0];
      u32 fa1 = pw0[i][1], fb1 = pw1[i][1];
      plswap(fa0, fb0);
      plswap(fa1, fb1);
      union { u32 u[4]; bf16x8 v; } fu;
      fu.u[0] = fa0; fu.u[1] = fa1; fu.u[2] = fb0; fu.u[3] = fb1;
      const bf16x8 pb = fu.v;
      o[i][0] = __builtin_amdgcn_mfma_f32_16x16x32_bf16(v0, pb, o[i][0], 0, 0, 0);
      o[i][1] = __builtin_amdgcn_mfma_f32_16x16x32_bf16(v1, pb, o[i][1], 0, 0, 0);
      o[i][2] = __builtin_amdgcn_mfma_f32_16x16x32_bf16(v2, pb, o[i][2], 0, 0, 0);
      o[i][3] = __builtin_amdgcn_mfma_f32_16x16x32_bf16(v3, pb, o[i][3], 0, 0, 0);
    }
  };

  const int split = (qt + 1) >> 1;
  const int itLo = wk ? split*4 : 0;
  const int itHi = wk ? qt*4 : split*4;
  if (itHi > itLo) {
    bf16x8 ak00, ak01, ak10, ak11;   // K buffer A
    bf16x8 bk00, bk01, bk10, bk11;   // K buffer B
    kissue(itLo, ak00, ak01, ak10, ak11);
    int it = itLo;
    while (true) {
      if (it + 1 < itHi) kissue(it + 1, bk00, bk01, bk10, bk11);
      compute(it, ak00, ak01, ak10, ak11);
      ++it; if (it == itHi) break;
      if (it + 1 < itHi) kissue(it + 1, ak00, ak01, ak10, ak11);
      compute(it, bk00, bk01, bk10, bk11);
      ++it; if (it == itHi) break;
    }
  }

  // -------- diagonal tile (kt == qt): wk=1 only; masked, ks up to wave's row range ----
  if (wk) {
    const int kt = qt;
    const int ksmax = 2*wq + 2; // wq=0: keys 0..63 (ks 0..1); wq=1: keys 0..127 (ks 0..3)
    const u16* kts = Kp + (long)(kt*128 + l16)*P_;
    for (int ks = 0; ks < ksmax; ++ks) {
      const u16* vp = Vp + (long)l16*S_ + kt*128 + ks*32 + quad*8;
      bf16x8 v0 = *(const bf16x8*)(vp);
      bf16x8 v1 = *(const bf16x8*)(vp + 16*S_);
      bf16x8 v2 = *(const bf16x8*)(vp + 32*S_);
      bf16x8 v3 = *(const bf16x8*)(vp + 48*S_);
      u32 pw[4][2][2];          // [i][jp][c]
      #pragma unroll
      for (int jp = 0; jp < 2; ++jp) {
        const int j = 2*ks + jp;
        const u16* kp = kts + (long)(j*16)*P_;
        bf16x8 kf0 = *(const bf16x8*)(kp + quad*8);
        bf16x8 kf1 = *(const bf16x8*)(kp + 32 + quad*8);
        const int kl0 = j*16 + quad*4;  // tile-local key of r=0
        const float bij = -sl2 * (float)(kt*128 + kl0);
        #pragma unroll
        for (int i = 0; i < 4; ++i) {
          const int ql = wq*64 + i*16 + l16;   // tile-local q row
          f32x4 t = {};
          t = __builtin_amdgcn_mfma_f32_16x16x32_bf16(kf0, qf[i][0], t, 0, 0, 0);
          t = __builtin_amdgcn_mfma_f32_16x16x32_bf16(kf1, qf[i][1], t, 0, 0, 0);
          float x0 = fmaf(t[0], c1, bij);
          float x1 = fmaf(t[1], c1, bij) - rs1;
          float x2 = fmaf(t[2], c1, bij) - rs2;
          float x3 = fmaf(t[3], c1, bij) - rs3;
          if (kl0 + 0 > ql) x0 = -1e30f;
          if (kl0 + 1 > ql) x1 = -1e30f;
          if (kl0 + 2 > ql) x2 = -1e30f;
          if (kl0 + 3 > ql) x3 = -1e30f;
          float p0 = __builtin_amdgcn_exp2f(x0);
          float p1 = __builtin_amdgcn_exp2f(x1);
          float p2 = __builtin_amdgcn_exp2f(x2);
          float p3 = __builtin_amdgcn_exp2f(x3);
          lsum[i] += (p0 + p1) + (p2 + p3);
          pw[i][jp][0] = pkbf(p0, p1);
          pw[i][jp][1] = pkbf(p2, p3);
        }
      }
      #pragma unroll
      for (int i = 0; i < 4; ++i) {
        u32 fa0 = pw[i][0][0], fb0 = pw[i][1][0];
        u32 fa1 = pw[i][0][1], fb1 = pw[i][1][1];
        plswap(fa0, fb0);
        plswap(fa1, fb1);
        union { u32 u[4]; bf16x8 v; } fu;
        fu.u[0] = fa0; fu.u[1] = fa1; fu.u[2] = fb0; fu.u[3] = fb1;
        const bf16x8 pb = fu.v;
        o[i][0] = __builtin_amdgcn_mfma_f32_16x16x32_bf16(v0, pb, o[i][0], 0, 0, 0);
        o[i][1] = __builtin_amdgcn_mfma_f32_16x16x32_bf16(v1, pb, o[i][1], 0, 0, 0);
        o[i][2] = __builtin_amdgcn_mfma_f32_16x16x32_bf16(v2, pb, o[i][2], 0, 0, 0);
        o[i][3] = __builtin_amdgcn_mfma_f32_16x16x32_bf16(v3, pb, o[i][3], 0, 0, 0);
      }
    }
  }

  // -------- combine kt-halves through LDS (lane-stride-1: conflict-free) --------
  __shared__ float Lo[2][4][4][4][64];   // [wq][i][jn][r][lane] = 32 KB
  __shared__ float Ls[2][4][64];         // [wq][i][lane]        =  2 KB
  if (!wk) {
    #pragma unroll
    for (int i = 0; i < 4; ++i) {
      #pragma unroll
      for (int jn = 0; jn < 4; ++jn)
        #pragma unroll
        for (int r = 0; r < 4; ++r)
          Lo[wq][i][jn][r][l] = o[i][jn][r];
      Ls[wq][i][l] = lsum[i];
    }
  }
  __syncthreads();
  if (wk) {
    #pragma unroll
    for (int i = 0; i < 4; ++i) {
      #pragma unroll
      for (int jn = 0; jn < 4; ++jn)
        #pragma unroll
        for (int r = 0; r < 4; ++r)
          o[i][jn][r] += Lo[wq][i][jn][r][l];
      lsum[i] += Ls[wq][i][l];
    }
    // -------- epilogue: reduce lsum across quads, scale, store (8B per lane-chunk) ----
    #pragma unroll
    for (int i = 0; i < 4; ++i) {
      lsum[i] += __shfl_xor(lsum[i], 16, 64);
      lsum[i] += __shfl_xor(lsum[i], 32, 64);
      const float inv = 1.0f / lsum[i];
      #pragma unroll
      for (int jn = 0; jn < 4; ++jn) {
        float v0 = o[i][jn][0] * inv, v1 = o[i][jn][1] * inv;
        float v2 = o[i][jn][2] * inv, v3 = o[i][jn][3] * inv;
        uint2 pk;
        pk.x = (u32)f2bf(v0) | ((u32)f2bf(v1) << 16);
        pk.y = (u32)f2bf(v2) | ((u32)f2bf(v3) << 16);
        *(uint2*)&Ob[((long)(b*S_ + q0 + i*16 + l16))*P_ + h*KD_ + jn*16 + quad*4] = pk;
      }
    }
  }
}

extern "C" void kernel_launch(void* const* d_in, const int* in_sizes, int n_in,
                              void* d_out, int out_size, void* d_ws, size_t ws_size,
                              hipStream_t stream) {
  const float* q  = (const float*)d_in[0];
  const float* k  = (const float*)d_in[1];
  const float* v  = (const float*)d_in[2];
  const float* Wq = (const float*)d_in[3];
  const float* bq = (const float*)d_in[4];
  const float* Wk = (const float*)d_in[5];
  const float* bk = (const float*)d_in[6];
  const float* Wv = (const float*)d_in[7];
  const float* bv = (const float*)d_in[8];
  const float* Wo = (const float*)d_in[9];
  const float* bo = (const float*)d_in[10];

  const size_t X_ELEMS = (size_t)M_ * P_;
  const size_t W_ELEMS = (size_t)D_ * P_;
  u16* ws  = (u16*)d_ws;
  u16* Xq  = ws;
  u16* Xk  = Xq  + X_ELEMS;
  u16* Xv  = Xk  + X_ELEMS;
  u16* WqT = Xv  + X_ELEMS;
  u16* WkT = WqT + W_ELEMS;
  u16* WvT = WkT + W_ELEMS;
  u16* WoT = WvT + W_ELEMS;
  u16* Qb  = WoT + W_ELEMS;
  u16* Kb  = Qb  + X_ELEMS;
  u16* Vt  = Kb  + X_ELEMS;      // transposed V: [b][h][d][s]
  u16* Attn = Xq;                // reuse: Xq dead after projections

  cvt3_kernel<<<dim3((unsigned)(X_ELEMS/4/256), 3), 256, 0, stream>>>(q, k, v, Xq, Xk, Xv);

  transpose_cvt4<<<dim3(32, 32, 4), dim3(32, 8), 0, stream>>>(Wq, Wk, Wv, Wo,
                                                              WqT, WkT, WvT, WoT);

  gemm_qkv<<<dim3(M_/128, P_/128, 3), 256, 0, stream>>>(Xq, Xk, Xv, WqT, WkT, WvT,
                                                        bq, bk, bv, Qb, Kb, Vt);

  attn_kernel<<<dim3(1024), 256, 0, stream>>>(Qb, Kb, Vt, Attn);

  gemm_out<<<dim3(M_/128, P_/128), 256, 0, stream>>>(Attn, WoT, bo, (float*)d_out);
}